// Round 1
// baseline (17942.667 us; speedup 1.0000x reference)
//
#include <hip/hip_runtime.h>
#include <cstddef>

// ---------------------------------------------------------------------------
// Detect head: per level, two branches conv3x3(C->C)+bias -> conv1x1(C->24/27)
// -> decode. fp32 baseline (correctness-first). CDNA4 has no fp32 MFMA; this
// round is VALU-bound by design, MFMA port comes next.
// ---------------------------------------------------------------------------

#define TOT_ANCH 25200

__device__ __forceinline__ float sig_(float x) { return 1.0f / (1.0f + __expf(-x)); }

// anchors[level][a][2]
__device__ const float d_anch[3][3][2] = {
    {{10.f, 13.f}, {16.f, 30.f}, {33.f, 23.f}},
    {{30.f, 61.f}, {62.f, 45.f}, {59.f, 119.f}},
    {{116.f, 90.f}, {156.f, 198.f}, {373.f, 326.f}}};

// ---------------------------------------------------------------------------
// conv3x3 (pad 1, C->C) + bias. One block: TW x TH spatial tile, COPB output
// channels, one batch. LDS stages one input-channel plane tile (with halo)
// per ci iteration; each thread reads its 3x3 window once into registers and
// does COPB*9 FMAs -> 36 FMA per 9 LDS b32 reads.
// grid: (ntx*nty, C/COPB, B)   block: TW*TH
// ---------------------------------------------------------------------------
template <int TW, int TH, int COPB>
__global__ void conv3x3_bias(const float* __restrict__ f, const float* __restrict__ w,
                             const float* __restrict__ bias, float* __restrict__ out,
                             int C, int H, int W) {
  constexpr int LW = TW + 2, LH = TH + 2;
  __shared__ float tileS[LH * LW];

  const int ntx = (W + TW - 1) / TW;
  const int tx0 = (blockIdx.x % ntx) * TW;
  const int ty0 = (blockIdx.x / ntx) * TH;
  const int cog = blockIdx.y;   // output-channel group
  const int b = blockIdx.z;
  const int t = threadIdx.x;
  const int lx = t % TW, ly = t / TW;
  const int ox = tx0 + lx, oy = ty0 + ly;

  float acc[COPB];
#pragma unroll
  for (int j = 0; j < COPB; ++j) acc[j] = 0.f;

  const size_t HW = (size_t)H * W;
  const float* fb = f + (size_t)b * C * HW;
  const size_t wstride = (size_t)C * 9;
  const float* wp = w + (size_t)(cog * COPB) * wstride;

  for (int ci = 0; ci < C; ++ci) {
    const float* fc = fb + (size_t)ci * HW;
    for (int idx = t; idx < LW * LH; idx += TW * TH) {
      int llx = idx % LW, lly = idx / LW;
      int gx = tx0 + llx - 1, gy = ty0 + lly - 1;
      float v = 0.f;
      if (gx >= 0 && gx < W && gy >= 0 && gy < H) v = fc[(size_t)gy * W + gx];
      tileS[idx] = v;
    }
    __syncthreads();

    float r[9];
#pragma unroll
    for (int ky = 0; ky < 3; ++ky)
#pragma unroll
      for (int kx = 0; kx < 3; ++kx) r[ky * 3 + kx] = tileS[(ly + ky) * LW + (lx + kx)];

    const float* wc = wp + (size_t)ci * 9;
#pragma unroll
    for (int j = 0; j < COPB; ++j) {
      const float* wj = wc + (size_t)j * wstride;
#pragma unroll
      for (int k = 0; k < 9; ++k) acc[j] = fmaf(r[k], wj[k], acc[j]);
    }
    __syncthreads();
  }

  if (ox < W && oy < H) {
#pragma unroll
    for (int j = 0; j < COPB; ++j) {
      int co = cog * COPB + j;
      out[((size_t)b * C + co) * HW + (size_t)oy * W + ox] = acc[j] + bias[co];
    }
  }
}

// ---------------------------------------------------------------------------
// 1x1 conv (C->24) + bias + 2D decode. One thread per (b, y, x); 24
// accumulators; h reads coalesced across threads for each ci. Writes channels
// 0..7 of the 17-channel output for the 3 anchors.
// ---------------------------------------------------------------------------
__global__ void decode2d(const float* __restrict__ h, const float* __restrict__ wb,
                         const float* __restrict__ bb, float* __restrict__ out,
                         int C, int H, int W, int B, int loff, float stride_, int lvl) {
  const int HW = H * W;
  int idx = blockIdx.x * blockDim.x + threadIdx.x;
  if (idx >= B * HW) return;
  const int b = idx / HW;
  const int p = idx % HW;
  const int y = p / W, x = p % W;

  float acc[24];
#pragma unroll
  for (int j = 0; j < 24; ++j) acc[j] = bb[j];

  const float* hb = h + (size_t)b * C * HW + p;
  for (int c = 0; c < C; ++c) {
    float v = hb[(size_t)c * HW];
#pragma unroll
    for (int j = 0; j < 24; ++j) acc[j] = fmaf(v, wb[(size_t)j * C + c], acc[j]);
  }

#pragma unroll
  for (int a = 0; a < 3; ++a) {
    float* o = out + ((size_t)b * TOT_ANCH + loff + (size_t)a * HW + p) * 17;
    float s0 = sig_(acc[a * 8 + 0]);
    float s1 = sig_(acc[a * 8 + 1]);
    float sw = sig_(acc[a * 8 + 2]) * 2.f;
    float sh = sig_(acc[a * 8 + 3]) * 2.f;
    o[0] = (s0 * 2.f - 0.5f + (float)x) * stride_;
    o[1] = (s1 * 2.f - 0.5f + (float)y) * stride_;
    o[2] = sw * sw * d_anch[lvl][a][0];
    o[3] = sh * sh * d_anch[lvl][a][1];
    o[4] = sig_(acc[a * 8 + 4]);
    o[5] = sig_(acc[a * 8 + 5]);
    o[6] = sig_(acc[a * 8 + 6]);
    o[7] = sig_(acc[a * 8 + 7]);
  }
}

// ---------------------------------------------------------------------------
// 1x1 conv (C->27) + bias + 3D decode. Writes channels 8..16.
// ---------------------------------------------------------------------------
__global__ void decode3d(const float* __restrict__ h, const float* __restrict__ wb,
                         const float* __restrict__ bb, float* __restrict__ out,
                         int C, int H, int W, int B, int loff) {
  const int HW = H * W;
  int idx = blockIdx.x * blockDim.x + threadIdx.x;
  if (idx >= B * HW) return;
  const int b = idx / HW;
  const int p = idx % HW;

  float acc[27];
#pragma unroll
  for (int j = 0; j < 27; ++j) acc[j] = bb[j];

  const float* hb = h + (size_t)b * C * HW + p;
  for (int c = 0; c < C; ++c) {
    float v = hb[(size_t)c * HW];
#pragma unroll
    for (int j = 0; j < 27; ++j) acc[j] = fmaf(v, wb[(size_t)j * C + c], acc[j]);
  }

#pragma unroll
  for (int a = 0; a < 3; ++a) {
    float* o = out + ((size_t)b * TOT_ANCH + loff + (size_t)a * HW + p) * 17;
    const float* v = &acc[a * 9];
    o[8] = v[0];
    o[9] = v[1];
    float n0 = fmaxf(sqrtf(v[2] * v[2] + v[3] * v[3]), 1e-12f);
    float n1 = fmaxf(sqrtf(v[4] * v[4] + v[5] * v[5]), 1e-12f);
    o[10] = v[2] / n0;
    o[11] = v[3] / n0;
    o[12] = v[4] / n1;
    o[13] = v[5] / n1;
    o[14] = sig_(v[6]) * 2.f - 1.f;
    o[15] = sig_(v[7]) * 2.f - 1.f;
    o[16] = sig_(v[8]) * 2.f - 1.f;
  }
}

// ---------------------------------------------------------------------------

extern "C" void kernel_launch(void* const* d_in, const int* in_sizes, int n_in,
                              void* d_out, int out_size, void* d_ws, size_t ws_size,
                              hipStream_t stream) {
  (void)in_sizes; (void)n_in; (void)out_size; (void)ws_size;
  float* ws = (float*)d_ws;       // holds one conv3x3 output: max 8*256*80*80 f32 = 52.4 MB
  float* out = (float*)d_out;

  struct Lvl { int C, H, W, loff; float stride; };
  const Lvl L[3] = {{256, 80, 80, 0, 8.f}, {512, 40, 40, 19200, 16.f}, {1024, 20, 20, 24000, 32.f}};
  const int B = 8;

  for (int i = 0; i < 3; ++i) {
    const float* f   = (const float*)d_in[9 * i + 0];
    const float* w2a = (const float*)d_in[9 * i + 1];
    const float* b2a = (const float*)d_in[9 * i + 2];
    const float* w2b = (const float*)d_in[9 * i + 3];
    const float* b2b = (const float*)d_in[9 * i + 4];
    const float* w3a = (const float*)d_in[9 * i + 5];
    const float* b3a = (const float*)d_in[9 * i + 6];
    const float* w3b = (const float*)d_in[9 * i + 7];
    const float* b3b = (const float*)d_in[9 * i + 8];

    const int C = L[i].C, H = L[i].H, W = L[i].W;
    const int HW = H * W;
    const int dec_threads = 256;
    const int dec_blocks = (B * HW + dec_threads - 1) / dec_threads;

    for (int br = 0; br < 2; ++br) {
      const float* wa = br == 0 ? w2a : w3a;
      const float* ba = br == 0 ? b2a : b3a;
      // conv3x3 -> ws. Tile shapes chosen for exact coverage per level:
      //  L0: 16x16 (80 divisible), L1: 40x8 (320 thr = 5 waves), L2: 20x20 (400 thr)
      if (i == 0) {
        conv3x3_bias<16, 16, 4><<<dim3(25, C / 4, B), 256, 0, stream>>>(f, wa, ba, ws, C, H, W);
      } else if (i == 1) {
        conv3x3_bias<40, 8, 4><<<dim3(5, C / 4, B), 320, 0, stream>>>(f, wa, ba, ws, C, H, W);
      } else {
        conv3x3_bias<20, 20, 4><<<dim3(1, C / 4, B), 400, 0, stream>>>(f, wa, ba, ws, C, H, W);
      }
      if (br == 0) {
        decode2d<<<dec_blocks, dec_threads, 0, stream>>>(ws, w2b, b2b, out, C, H, W, B,
                                                         L[i].loff, L[i].stride, i);
      } else {
        decode3d<<<dec_blocks, dec_threads, 0, stream>>>(ws, w3b, b3b, out, C, H, W, B,
                                                         L[i].loff);
      }
    }
  }
}

// Round 2
// 1830.009 us; speedup vs baseline: 9.8047x; 9.8047x over previous
//
#include <hip/hip_runtime.h>
#include <hip/hip_bf16.h>
#include <cstddef>
#include <cstdint>

#define TOT_ANCH 25200

typedef __bf16 bf16x8 __attribute__((ext_vector_type(8)));
typedef float f32x4 __attribute__((ext_vector_type(4)));

__device__ __forceinline__ float sig_(float x) { return 1.0f / (1.0f + __expf(-x)); }

__device__ __forceinline__ short f2bf(float v) {
  return (short)__builtin_bit_cast(unsigned short, __float2bfloat16(v));
}
__device__ __forceinline__ float bf2f(short v) {
  unsigned int u = ((unsigned int)(unsigned short)v) << 16;
  return __builtin_bit_cast(float, u);
}
__device__ __forceinline__ bf16x8 as_bf16x8(int4 v) { return __builtin_bit_cast(bf16x8, v); }

__device__ __forceinline__ void gload_lds16(const void* g, void* l) {
  __builtin_amdgcn_global_load_lds((const __attribute__((address_space(1))) void*)g,
                                   (__attribute__((address_space(3))) void*)l, 16, 0, 0);
}

// anchors[level][a][2]
__device__ const float d_anch[3][3][2] = {
    {{10.f, 13.f}, {16.f, 30.f}, {33.f, 23.f}},
    {{30.f, 61.f}, {62.f, 45.f}, {59.f, 119.f}},
    {{116.f, 90.f}, {156.f, 198.f}, {373.f, 326.f}}};

// ---------------------------------------------------------------------------
// f32 NCHW -> bf16 NHWC  (i enumerates output: ((b*HW+p)*C + c))
// ---------------------------------------------------------------------------
__global__ void to_nhwc_bf16(const float* __restrict__ f, short* __restrict__ fb,
                             int HW, int csh, long total) {
  long i = (long)blockIdx.x * blockDim.x + threadIdx.x;
  if (i >= total) return;
  int C = 1 << csh;
  long c = i & (C - 1);
  long bp = i >> csh;
  long b = bp / HW;
  long p = bp - b * HW;
  fb[i] = f2bf(f[(b * C + c) * HW + p]);
}

// ---------------------------------------------------------------------------
// w[o][i][t] f32 (OIHW, 3x3) -> wt[t][o][i] bf16
// ---------------------------------------------------------------------------
__global__ void wt_transform(const float* __restrict__ w, short* __restrict__ wt, long CC) {
  long oi = (long)blockIdx.x * blockDim.x + threadIdx.x;
  if (oi >= CC) return;
#pragma unroll
  for (int t = 0; t < 9; ++t) wt[t * CC + oi] = f2bf(w[oi * 9 + t]);
}

// ---------------------------------------------------------------------------
// Implicit-GEMM conv3x3 (pad 1) via mfma_f32_16x16x32_bf16.
//   D[M=C_out][N=Bg*HW] = sum_tap Wt[tap] (MxC) * Xshift (CxN), + bias.
// 128x128 tile, BK=64, 4 waves (2x2) of 4x4 16x16 fragments.
// LDS tiles [128][64] bf16, 16B-chunk XOR swizzle (chunk ^ (row&7)):
// linear LDS dest for global_load_lds, pre-swizzled global src, swizzled read.
// fb: NHWC bf16; wt: [9][C][C] bf16; h out: NCHW bf16 (per batch-group).
// grid: (Ng/128, C/128), block 256.
// ---------------------------------------------------------------------------
__global__ __launch_bounds__(256) void conv3x3_mfma(
    const short* __restrict__ fb, const short* __restrict__ wt,
    const float* __restrict__ bias, short* __restrict__ h,
    const short* __restrict__ zbuf, int C, int H, int W, int HW) {
  __shared__ __align__(16) short As[128 * 64];
  __shared__ __align__(16) short Xs[128 * 64];

  const int tid = threadIdx.x;
  const int lane = tid & 63;
  const int wave = tid >> 6;
  const int wm = (wave >> 1) * 64;
  const int wn = (wave & 1) * 64;
  const int nt0 = blockIdx.x * 128;
  const int mt0 = blockIdx.y * 128;
  const int s = tid & 7;  // 16B chunk slot within a 128B row

  // staging precompute: 4 rounds, each stages 32 rows/cols x 64 k (16B/lane)
  int xs_x[4], xs_y[4];
  int xs_base[4];  // element offset of (b,y,x, swizzled chunk) in fb
  int as_base[4];  // element offset within one tap's [C][C] weight block
#pragma unroll
  for (int r = 0; r < 4; ++r) {
    int cl = r * 32 + (tid >> 3);  // tile-local col/row index
    int n = nt0 + cl;
    int b = n / HW; int p = n - b * HW;
    int y = p / W;  int x = p - y * W;
    xs_x[r] = x; xs_y[r] = y;
    int swz = (s ^ (cl & 7)) * 8;
    xs_base[r] = ((b * H + y) * W + x) * C + swz;
    as_base[r] = (mt0 + cl) * C + swz;
  }

  f32x4 acc[4][4];
#pragma unroll
  for (int a_ = 0; a_ < 4; ++a_)
#pragma unroll
    for (int b_ = 0; b_ < 4; ++b_) acc[a_][b_] = (f32x4){0.f, 0.f, 0.f, 0.f};

  const int nkb = C >> 6;
  const short* gzb = zbuf + s * 8;

  for (int t = 0; t < 9; ++t) {
    const int dy = t / 3 - 1, dx = t - (t / 3) * 3 - 1;
    const short* gxp[4];
    bool okf[4];
#pragma unroll
    for (int r = 0; r < 4; ++r) {
      bool ok = ((unsigned)(xs_y[r] + dy) < (unsigned)H) &
                ((unsigned)(xs_x[r] + dx) < (unsigned)W);
      okf[r] = ok;
      gxp[r] = ok ? fb + xs_base[r] + (dy * W + dx) * C : gzb;
    }
    const short* gap = wt + (long)t * C * C;

    for (int kb = 0; kb < nkb; ++kb) {
      const int kb64 = kb << 6;
#pragma unroll
      for (int r = 0; r < 4; ++r) {
        gload_lds16(gap + as_base[r] + kb64, (char*)As + r * 4096 + tid * 16);
        const short* gx = okf[r] ? gxp[r] + kb64 : gxp[r];
        gload_lds16(gx, (char*)Xs + r * 4096 + tid * 16);
      }
      __syncthreads();  // drains vmcnt -> LDS tiles complete

#pragma unroll
      for (int ks = 0; ks < 2; ++ks) {
        bf16x8 af[4], xf[4];
#pragma unroll
        for (int mf = 0; mf < 4; ++mf) {
          int row = wm + mf * 16 + (lane & 15);
          int c = (ks * 4 + (lane >> 4)) ^ (row & 7);
          af[mf] = as_bf16x8(*(const int4*)((const char*)As + row * 128 + c * 16));
        }
#pragma unroll
        for (int nf = 0; nf < 4; ++nf) {
          int col = wn + nf * 16 + (lane & 15);
          int c = (ks * 4 + (lane >> 4)) ^ (col & 7);
          xf[nf] = as_bf16x8(*(const int4*)((const char*)Xs + col * 128 + c * 16));
        }
#pragma unroll
        for (int mf = 0; mf < 4; ++mf)
#pragma unroll
          for (int nf = 0; nf < 4; ++nf)
            acc[mf][nf] = __builtin_amdgcn_mfma_f32_16x16x32_bf16(af[mf], xf[nf],
                                                                  acc[mf][nf], 0, 0, 0);
      }
      __syncthreads();  // protect LDS from next stage
    }
  }

  // epilogue: + bias, store bf16 NCHW: h[(b*C+co)*HW + p]
  int nb[4], np[4];
#pragma unroll
  for (int nf = 0; nf < 4; ++nf) {
    int n = nt0 + wn + nf * 16 + (lane & 15);
    nb[nf] = n / HW;
    np[nf] = n - nb[nf] * HW;
  }
#pragma unroll
  for (int mf = 0; mf < 4; ++mf) {
    int co0 = mt0 + wm + mf * 16 + (lane >> 4) * 4;
#pragma unroll
    for (int rg = 0; rg < 4; ++rg) {
      float bv = bias[co0 + rg];
#pragma unroll
      for (int nf = 0; nf < 4; ++nf) {
        float v = acc[mf][nf][rg] + bv;
        h[((long)nb[nf] * C + co0 + rg) * HW + np[nf]] = f2bf(v);
      }
    }
  }
}

// ---------------------------------------------------------------------------
// 1x1 conv (C->24) + bias + 2D decode (channels 0..7), h in bf16 NCHW.
// ---------------------------------------------------------------------------
__global__ void decode2d(const short* __restrict__ h, const float* __restrict__ wb,
                         const float* __restrict__ bb, float* __restrict__ out,
                         int C, int H, int W, int Bg, int b0, int loff, float stride_,
                         int lvl) {
  const int HW = H * W;
  int idx = blockIdx.x * blockDim.x + threadIdx.x;
  if (idx >= Bg * HW) return;
  const int bl = idx / HW;
  const int p = idx % HW;
  const int y = p / W, x = p % W;

  float acc[24];
#pragma unroll
  for (int j = 0; j < 24; ++j) acc[j] = bb[j];

  const short* hb = h + (size_t)bl * C * HW + p;
  for (int c = 0; c < C; ++c) {
    float v = bf2f(hb[(size_t)c * HW]);
#pragma unroll
    for (int j = 0; j < 24; ++j) acc[j] = fmaf(v, wb[(size_t)j * C + c], acc[j]);
  }

#pragma unroll
  for (int a = 0; a < 3; ++a) {
    float* o = out + ((size_t)(b0 + bl) * TOT_ANCH + loff + (size_t)a * HW + p) * 17;
    float s0 = sig_(acc[a * 8 + 0]);
    float s1 = sig_(acc[a * 8 + 1]);
    float sw = sig_(acc[a * 8 + 2]) * 2.f;
    float sh = sig_(acc[a * 8 + 3]) * 2.f;
    o[0] = (s0 * 2.f - 0.5f + (float)x) * stride_;
    o[1] = (s1 * 2.f - 0.5f + (float)y) * stride_;
    o[2] = sw * sw * d_anch[lvl][a][0];
    o[3] = sh * sh * d_anch[lvl][a][1];
    o[4] = sig_(acc[a * 8 + 4]);
    o[5] = sig_(acc[a * 8 + 5]);
    o[6] = sig_(acc[a * 8 + 6]);
    o[7] = sig_(acc[a * 8 + 7]);
  }
}

// ---------------------------------------------------------------------------
// 1x1 conv (C->27) + bias + 3D decode (channels 8..16), h in bf16 NCHW.
// ---------------------------------------------------------------------------
__global__ void decode3d(const short* __restrict__ h, const float* __restrict__ wb,
                         const float* __restrict__ bb, float* __restrict__ out,
                         int C, int H, int W, int Bg, int b0, int loff) {
  const int HW = H * W;
  int idx = blockIdx.x * blockDim.x + threadIdx.x;
  if (idx >= Bg * HW) return;
  const int bl = idx / HW;
  const int p = idx % HW;

  float acc[27];
#pragma unroll
  for (int j = 0; j < 27; ++j) acc[j] = bb[j];

  const short* hb = h + (size_t)bl * C * HW + p;
  for (int c = 0; c < C; ++c) {
    float v = bf2f(hb[(size_t)c * HW]);
#pragma unroll
    for (int j = 0; j < 27; ++j) acc[j] = fmaf(v, wb[(size_t)j * C + c], acc[j]);
  }

#pragma unroll
  for (int a = 0; a < 3; ++a) {
    float* o = out + ((size_t)(b0 + bl) * TOT_ANCH + loff + (size_t)a * HW + p) * 17;
    const float* v = &acc[a * 9];
    o[8] = v[0];
    o[9] = v[1];
    float n0 = fmaxf(sqrtf(v[2] * v[2] + v[3] * v[3]), 1e-12f);
    float n1 = fmaxf(sqrtf(v[4] * v[4] + v[5] * v[5]), 1e-12f);
    o[10] = v[2] / n0;
    o[11] = v[3] / n0;
    o[12] = v[4] / n1;
    o[13] = v[5] / n1;
    o[14] = sig_(v[6]) * 2.f - 1.f;
    o[15] = sig_(v[7]) * 2.f - 1.f;
    o[16] = sig_(v[8]) * 2.f - 1.f;
  }
}

// ---------------------------------------------------------------------------

static inline size_t al256(size_t x) { return (x + 255) & ~(size_t)255; }

extern "C" void kernel_launch(void* const* d_in, const int* in_sizes, int n_in,
                              void* d_out, int out_size, void* d_ws, size_t ws_size,
                              hipStream_t stream) {
  (void)in_sizes; (void)n_in; (void)out_size;
  char* ws = (char*)d_ws;
  float* out = (float*)d_out;

  hipMemsetAsync(ws, 0, 256, stream);  // zero page for OOB tap columns

  struct Lvl { int C, H, W, loff; float stride; };
  const Lvl L[3] = {{256, 80, 80, 0, 8.f}, {512, 40, 40, 19200, 16.f},
                    {1024, 20, 20, 24000, 32.f}};
  const int B = 8;

  for (int i = 0; i < 3; ++i) {
    const float* f   = (const float*)d_in[9 * i + 0];
    const float* w2a = (const float*)d_in[9 * i + 1];
    const float* b2a = (const float*)d_in[9 * i + 2];
    const float* w2b = (const float*)d_in[9 * i + 3];
    const float* b2b = (const float*)d_in[9 * i + 4];
    const float* w3a = (const float*)d_in[9 * i + 5];
    const float* b3a = (const float*)d_in[9 * i + 6];
    const float* w3b = (const float*)d_in[9 * i + 7];
    const float* b3b = (const float*)d_in[9 * i + 8];

    const int C = L[i].C, H = L[i].H, W = L[i].W, HW = H * W;
    const int csh = (C == 256) ? 8 : (C == 512) ? 9 : 10;
    const long CC = (long)C * C;

    // batch-group split only if ws is too small for level-0 single pass
    int nbg = 1;
    if (i == 0) {
      size_t need = 256 + al256((size_t)B * HW * C * 2) + al256((size_t)9 * CC * 2) +
                    (size_t)B * C * HW * 2 + 1024;
      if (ws_size < need) nbg = 2;
    }
    const int Bg = B / nbg;

    size_t fb_off = 256;
    size_t wt_off = fb_off + al256((size_t)Bg * HW * C * 2);
    size_t h_off  = wt_off + al256((size_t)9 * CC * 2);
    short* fb = (short*)(ws + fb_off);
    short* wtb = (short*)(ws + wt_off);
    short* hb = (short*)(ws + h_off);
    const short* zb = (const short*)ws;

    for (int g = 0; g < nbg; ++g) {
      const int b0 = g * Bg;
      const long total = (long)Bg * HW * C;
      to_nhwc_bf16<<<(int)((total + 255) / 256), 256, 0, stream>>>(
          f + (size_t)b0 * C * HW, fb, HW, csh, total);

      const int Ng = Bg * HW;
      const int dec_blocks = (Ng + 255) / 256;
      for (int br = 0; br < 2; ++br) {
        const float* wa = br ? w3a : w2a;
        const float* ba = br ? b3a : b2a;
        wt_transform<<<(int)((CC + 255) / 256), 256, 0, stream>>>(wa, wtb, CC);
        conv3x3_mfma<<<dim3(Ng / 128, C / 128), 256, 0, stream>>>(
            fb, wtb, ba, hb, zb, C, H, W, HW);
        if (br == 0) {
          decode2d<<<dec_blocks, 256, 0, stream>>>(hb, w2b, b2b, out, C, H, W, Bg, b0,
                                                   L[i].loff, L[i].stride, i);
        } else {
          decode3d<<<dec_blocks, 256, 0, stream>>>(hb, w3b, b3b, out, C, H, W, Bg, b0,
                                                   L[i].loff);
        }
      }
    }
  }
}

// Round 4
// 888.612 us; speedup vs baseline: 20.1918x; 2.0594x over previous
//
#include <hip/hip_runtime.h>
#include <hip/hip_bf16.h>
#include <cstddef>
#include <cstdint>

#define TOT_ANCH 25200

typedef __bf16 bf16x8 __attribute__((ext_vector_type(8)));
typedef float f32x4 __attribute__((ext_vector_type(4)));

__device__ __forceinline__ float sig_(float x) { return 1.0f / (1.0f + __expf(-x)); }

__device__ __forceinline__ short f2bf(float v) {
  return (short)__builtin_bit_cast(unsigned short, __float2bfloat16(v));
}
__device__ __forceinline__ float bf2f(short v) {
  unsigned int u = ((unsigned int)(unsigned short)v) << 16;
  return __builtin_bit_cast(float, u);
}
__device__ __forceinline__ bf16x8 as_bf16x8(int4 v) { return __builtin_bit_cast(bf16x8, v); }

__device__ __forceinline__ void gload_lds16(const void* g, void* l) {
  __builtin_amdgcn_global_load_lds((const __attribute__((address_space(1))) void*)g,
                                   (__attribute__((address_space(3))) void*)l, 16, 0, 0);
}

// anchors[level][a][2]
__device__ const float d_anch[3][3][2] = {
    {{10.f, 13.f}, {16.f, 30.f}, {33.f, 23.f}},
    {{30.f, 61.f}, {62.f, 45.f}, {59.f, 119.f}},
    {{116.f, 90.f}, {156.f, 198.f}, {373.f, 326.f}}};

// ---------------------------------------------------------------------------
// f32 NCHW -> bf16 NHWC, LDS 32x32 tile, coalesced both sides.
// grid: (ceil(HW/32), C/32, Bg), block 256. Handles HW % 32 != 0 (L2: 400).
// ---------------------------------------------------------------------------
__global__ __launch_bounds__(256) void to_nhwc_tile(const float* __restrict__ f,
                                                    short* __restrict__ fb, int C, int HW) {
  __shared__ short tile[32][33];
  const int p0 = blockIdx.x * 32, c0 = blockIdx.y * 32, b = blockIdx.z;
  const int t = threadIdx.x;
  {
    int cl = t >> 3, pl = (t & 7) * 4;
    int pr = p0 + pl;
    if (pr > HW - 4) pr = HW - 4;  // clamp: stays %4==0 (HW%4==0), dup data unused
    const float4 v = *(const float4*)(f + ((long)b * C + c0 + cl) * HW + pr);
    tile[cl][pl + 0] = f2bf(v.x);
    tile[cl][pl + 1] = f2bf(v.y);
    tile[cl][pl + 2] = f2bf(v.z);
    tile[cl][pl + 3] = f2bf(v.w);
  }
  __syncthreads();
  {
    int pl = t >> 3, cl = (t & 7) * 4;
    if (p0 + pl < HW) {
      // note: if p0+pl fell in the clamped duplicate zone we must recompute
      // from the true source. Only the last partial tile hits this; values in
      // tile[] for pl rows beyond the clamp base are duplicates of HW-4..HW-1.
      // Since clamping maps reads of pixel q>=HW-? incorrectly only for
      // pixels >= HW (guarded here), rows pl with p0+pl < HW are correct:
      // clamp only triggers when p0+pl+3 > HW-1 i.e. p0+pl > HW-4; for those
      // in-range rows (HW-3..HW-1) the data landed at tile[cl][HW-4-p0 ..].
      int pp = p0 + pl;
      int src = pp;
      int base = (p0 + 28 > HW - 4) ? (HW - 4) : (p0 + 28);  // unused helper
      (void)base; (void)src;
      short4 o;
      // recompute column within tile: row r of tile holds pixels pr..pr+3
      // where pr = min(p0 + (r&~3? ...)) -- simpler: pixels were written in
      // groups of 4 starting at min(p0+4k, HW-4). Find group k = pl>>2,
      // start = min(p0+4k, HW-4), col index within tile = (start-p0)+(pp-start).
      int k = pl >> 2;
      int start = p0 + 4 * k;
      if (start > HW - 4) start = HW - 4;
      int col = (start - p0) + (pp - start);
      o.x = tile[cl + 0][col];
      o.y = tile[cl + 1][col];
      o.z = tile[cl + 2][col];
      o.w = tile[cl + 3][col];
      *(short4*)(fb + ((long)b * HW + pp) * C + c0 + cl) = o;
    }
  }
}

// ---------------------------------------------------------------------------
// w[o][i][t] f32 (OIHW, 3x3) -> wt[t][o][i] bf16 (writes coalesced over oi)
// ---------------------------------------------------------------------------
__global__ void wt_transform(const float* __restrict__ w, short* __restrict__ wt, long CC) {
  long oi = (long)blockIdx.x * blockDim.x + threadIdx.x;
  if (oi >= CC) return;
#pragma unroll
  for (int t = 0; t < 9; ++t) wt[t * CC + oi] = f2bf(w[oi * 9 + t]);
}

// ---------------------------------------------------------------------------
// Implicit-GEMM conv3x3 (pad 1) via mfma_f32_16x16x32_bf16. (unchanged, r2)
// 128x128 tile, BK=64, 4 waves (2x2) of 4x4 16x16 fragments, global_load_lds
// width-16, XOR chunk swizzle via pre-swizzled global source.
// ---------------------------------------------------------------------------
__global__ __launch_bounds__(256) void conv3x3_mfma(
    const short* __restrict__ fb, const short* __restrict__ wt,
    const float* __restrict__ bias, short* __restrict__ h,
    const short* __restrict__ zbuf, int C, int H, int W, int HW) {
  __shared__ __align__(16) short As[128 * 64];
  __shared__ __align__(16) short Xs[128 * 64];

  const int tid = threadIdx.x;
  const int lane = tid & 63;
  const int wave = tid >> 6;
  const int wm = (wave >> 1) * 64;
  const int wn = (wave & 1) * 64;
  const int nt0 = blockIdx.x * 128;
  const int mt0 = blockIdx.y * 128;
  const int s = tid & 7;

  int xs_x[4], xs_y[4];
  int xs_base[4];
  int as_base[4];
#pragma unroll
  for (int r = 0; r < 4; ++r) {
    int cl = r * 32 + (tid >> 3);
    int n = nt0 + cl;
    int b = n / HW; int p = n - b * HW;
    int y = p / W;  int x = p - y * W;
    xs_x[r] = x; xs_y[r] = y;
    int swz = (s ^ (cl & 7)) * 8;
    xs_base[r] = ((b * H + y) * W + x) * C + swz;
    as_base[r] = (mt0 + cl) * C + swz;
  }

  f32x4 acc[4][4];
#pragma unroll
  for (int a_ = 0; a_ < 4; ++a_)
#pragma unroll
    for (int b_ = 0; b_ < 4; ++b_) acc[a_][b_] = (f32x4){0.f, 0.f, 0.f, 0.f};

  const int nkb = C >> 6;
  const short* gzb = zbuf + s * 8;

  for (int t = 0; t < 9; ++t) {
    const int dy = t / 3 - 1, dx = t - (t / 3) * 3 - 1;
    const short* gxp[4];
    bool okf[4];
#pragma unroll
    for (int r = 0; r < 4; ++r) {
      bool ok = ((unsigned)(xs_y[r] + dy) < (unsigned)H) &
                ((unsigned)(xs_x[r] + dx) < (unsigned)W);
      okf[r] = ok;
      gxp[r] = ok ? fb + xs_base[r] + (dy * W + dx) * C : gzb;
    }
    const short* gap = wt + (long)t * C * C;

    for (int kb = 0; kb < nkb; ++kb) {
      const int kb64 = kb << 6;
#pragma unroll
      for (int r = 0; r < 4; ++r) {
        gload_lds16(gap + as_base[r] + kb64, (char*)As + r * 4096 + tid * 16);
        const short* gx = okf[r] ? gxp[r] + kb64 : gxp[r];
        gload_lds16(gx, (char*)Xs + r * 4096 + tid * 16);
      }
      __syncthreads();

#pragma unroll
      for (int ks = 0; ks < 2; ++ks) {
        bf16x8 af[4], xf[4];
#pragma unroll
        for (int mf = 0; mf < 4; ++mf) {
          int row = wm + mf * 16 + (lane & 15);
          int c = (ks * 4 + (lane >> 4)) ^ (row & 7);
          af[mf] = as_bf16x8(*(const int4*)((const char*)As + row * 128 + c * 16));
        }
#pragma unroll
        for (int nf = 0; nf < 4; ++nf) {
          int col = wn + nf * 16 + (lane & 15);
          int c = (ks * 4 + (lane >> 4)) ^ (col & 7);
          xf[nf] = as_bf16x8(*(const int4*)((const char*)Xs + col * 128 + c * 16));
        }
#pragma unroll
        for (int mf = 0; mf < 4; ++mf)
#pragma unroll
          for (int nf = 0; nf < 4; ++nf)
            acc[mf][nf] = __builtin_amdgcn_mfma_f32_16x16x32_bf16(af[mf], xf[nf],
                                                                  acc[mf][nf], 0, 0, 0);
      }
      __syncthreads();
    }
  }

  int nb[4], np[4];
#pragma unroll
  for (int nf = 0; nf < 4; ++nf) {
    int n = nt0 + wn + nf * 16 + (lane & 15);
    nb[nf] = n / HW;
    np[nf] = n - nb[nf] * HW;
  }
#pragma unroll
  for (int mf = 0; mf < 4; ++mf) {
    int co0 = mt0 + wm + mf * 16 + (lane >> 4) * 4;
#pragma unroll
    for (int rg = 0; rg < 4; ++rg) {
      float bv = bias[co0 + rg];
#pragma unroll
      for (int nf = 0; nf < 4; ++nf) {
        float v = acc[mf][nf][rg] + bv;
        h[((long)nb[nf] * C + co0 + rg) * HW + np[nf]] = f2bf(v);
      }
    }
  }
}

// ---------------------------------------------------------------------------
// decode v2: LDS-tiled 1x1 conv (C->NOUT) + bias + decode.
// grid: (ceil(HW/32), Bg) so no block crosses a batch plane (L2: HW=400).
// Block = 256 thr = 32 px (t&31) x 8 output-groups (t>>5) of 4 outputs.
// ---------------------------------------------------------------------------
template <int NOUT>
__global__ __launch_bounds__(256) void decode_v2(
    const short* __restrict__ h, const float* __restrict__ wb,
    const float* __restrict__ bb, float* __restrict__ out,
    int C, int H, int W, int b0, int loff, float stride_, int lvl) {
  __shared__ float htile[32][33];
  __shared__ float wtileT[32][32];
  __shared__ float otile[32][NOUT + 1];
  const int HW = H * W;
  const int t = threadIdx.x;
  const int p0 = blockIdx.x * 32;
  const int bl = blockIdx.y;
  const int px = t & 31, og = t >> 5;

  float acc[4] = {0.f, 0.f, 0.f, 0.f};
  const int nch = C >> 5;
  for (int ch = 0; ch < nch; ++ch) {
    const int c0 = ch << 5;
    {
      int cl = t >> 3, pl = (t & 7) * 4;
      int pr = p0 + pl;
      if (pr > HW - 4) pr = HW - 4;  // clamp; dup columns belong to dead px
      const short4 v = *(const short4*)(h + ((long)bl * C + c0 + cl) * HW + pr);
      htile[cl][pl + 0] = bf2f(v.x);
      htile[cl][pl + 1] = bf2f(v.y);
      htile[cl][pl + 2] = bf2f(v.z);
      htile[cl][pl + 3] = bf2f(v.w);
    }
    {
      int j = t >> 3, cl = (t & 7) * 4;
      if (j < NOUT) {
        const float4 v = *(const float4*)(wb + (long)j * C + c0 + cl);
        wtileT[cl + 0][j] = v.x;
        wtileT[cl + 1][j] = v.y;
        wtileT[cl + 2][j] = v.z;
        wtileT[cl + 3][j] = v.w;
      } else {
        wtileT[cl + 0][j] = 0.f;
        wtileT[cl + 1][j] = 0.f;
        wtileT[cl + 2][j] = 0.f;
        wtileT[cl + 3][j] = 0.f;
      }
    }
    __syncthreads();
#pragma unroll
    for (int c = 0; c < 32; ++c) {
      float v = htile[c][px];
      const float4 wv = *(const float4*)&wtileT[c][og * 4];
      acc[0] = fmaf(v, wv.x, acc[0]);
      acc[1] = fmaf(v, wv.y, acc[1]);
      acc[2] = fmaf(v, wv.z, acc[2]);
      acc[3] = fmaf(v, wv.w, acc[3]);
    }
    __syncthreads();
  }
#pragma unroll
  for (int g = 0; g < 4; ++g) {
    int j = og * 4 + g;
    if (j < NOUT) otile[px][j] = acc[g] + bb[j];
  }
  __syncthreads();

  // (px, anchor) tasks: 96 of them
  if (t < 96) {
    const int pxx = t / 3, a = t - (t / 3) * 3;
    const int p = p0 + pxx;
    if (p < HW) {
      float* o = out + ((size_t)(b0 + bl) * TOT_ANCH + loff + (size_t)a * HW + p) * 17;
      if (NOUT == 24) {
        const int y = p / W, x = p - (p / W) * W;
        float s0 = sig_(otile[pxx][a * 8 + 0]);
        float s1 = sig_(otile[pxx][a * 8 + 1]);
        float sw = sig_(otile[pxx][a * 8 + 2]) * 2.f;
        float sh = sig_(otile[pxx][a * 8 + 3]) * 2.f;
        o[0] = (s0 * 2.f - 0.5f + (float)x) * stride_;
        o[1] = (s1 * 2.f - 0.5f + (float)y) * stride_;
        o[2] = sw * sw * d_anch[lvl][a][0];
        o[3] = sh * sh * d_anch[lvl][a][1];
        o[4] = sig_(otile[pxx][a * 8 + 4]);
        o[5] = sig_(otile[pxx][a * 8 + 5]);
        o[6] = sig_(otile[pxx][a * 8 + 6]);
        o[7] = sig_(otile[pxx][a * 8 + 7]);
      } else {
        float v0 = otile[pxx][a * 9 + 0], v1 = otile[pxx][a * 9 + 1];
        float v2 = otile[pxx][a * 9 + 2], v3 = otile[pxx][a * 9 + 3];
        float v4 = otile[pxx][a * 9 + 4], v5 = otile[pxx][a * 9 + 5];
        float v6 = otile[pxx][a * 9 + 6], v7 = otile[pxx][a * 9 + 7];
        float v8 = otile[pxx][a * 9 + 8];
        float n0 = fmaxf(sqrtf(v2 * v2 + v3 * v3), 1e-12f);
        float n1 = fmaxf(sqrtf(v4 * v4 + v5 * v5), 1e-12f);
        o[8] = v0;
        o[9] = v1;
        o[10] = v2 / n0;
        o[11] = v3 / n0;
        o[12] = v4 / n1;
        o[13] = v5 / n1;
        o[14] = sig_(v6) * 2.f - 1.f;
        o[15] = sig_(v7) * 2.f - 1.f;
        o[16] = sig_(v8) * 2.f - 1.f;
      }
    }
  }
}

// ---------------------------------------------------------------------------

static inline size_t al256(size_t x) { return (x + 255) & ~(size_t)255; }

extern "C" void kernel_launch(void* const* d_in, const int* in_sizes, int n_in,
                              void* d_out, int out_size, void* d_ws, size_t ws_size,
                              hipStream_t stream) {
  (void)in_sizes; (void)n_in; (void)out_size;
  char* ws = (char*)d_ws;
  float* out = (float*)d_out;

  hipMemsetAsync(ws, 0, 256, stream);  // zero page for OOB tap columns

  struct Lvl { int C, H, W, loff; float stride; };
  const Lvl L[3] = {{256, 80, 80, 0, 8.f}, {512, 40, 40, 19200, 16.f},
                    {1024, 20, 20, 24000, 32.f}};
  const int B = 8;

  for (int i = 0; i < 3; ++i) {
    const float* f   = (const float*)d_in[9 * i + 0];
    const float* w2a = (const float*)d_in[9 * i + 1];
    const float* b2a = (const float*)d_in[9 * i + 2];
    const float* w2b = (const float*)d_in[9 * i + 3];
    const float* b2b = (const float*)d_in[9 * i + 4];
    const float* w3a = (const float*)d_in[9 * i + 5];
    const float* b3a = (const float*)d_in[9 * i + 6];
    const float* w3b = (const float*)d_in[9 * i + 7];
    const float* b3b = (const float*)d_in[9 * i + 8];

    const int C = L[i].C, H = L[i].H, W = L[i].W, HW = H * W;
    const long CC = (long)C * C;

    int nbg = 1;
    if (i == 0) {
      size_t need = 256 + al256((size_t)B * HW * C * 2) + al256((size_t)9 * CC * 2) +
                    (size_t)B * C * HW * 2 + 1024;
      if (ws_size < need) nbg = 2;
    }
    const int Bg = B / nbg;

    size_t fb_off = 256;
    size_t wt_off = fb_off + al256((size_t)Bg * HW * C * 2);
    size_t h_off  = wt_off + al256((size_t)9 * CC * 2);
    short* fb = (short*)(ws + fb_off);
    short* wtb = (short*)(ws + wt_off);
    short* hb = (short*)(ws + h_off);
    const short* zb = (const short*)ws;

    const int ptiles = (HW + 31) / 32;

    for (int g = 0; g < nbg; ++g) {
      const int b0 = g * Bg;
      to_nhwc_tile<<<dim3(ptiles, C / 32, Bg), 256, 0, stream>>>(
          f + (size_t)b0 * C * HW, fb, C, HW);

      const int Ng = Bg * HW;
      for (int br = 0; br < 2; ++br) {
        const float* wa = br ? w3a : w2a;
        const float* ba = br ? b3a : b2a;
        wt_transform<<<(int)((CC + 255) / 256), 256, 0, stream>>>(wa, wtb, CC);
        conv3x3_mfma<<<dim3(Ng / 128, C / 128), 256, 0, stream>>>(
            fb, wtb, ba, hb, zb, C, H, W, HW);
        if (br == 0) {
          decode_v2<24><<<dim3(ptiles, Bg), 256, 0, stream>>>(hb, w2b, b2b, out, C, H, W,
                                                              b0, L[i].loff, L[i].stride, i);
        } else {
          decode_v2<27><<<dim3(ptiles, Bg), 256, 0, stream>>>(hb, w3b, b3b, out, C, H, W,
                                                              b0, L[i].loff, L[i].stride, i);
        }
      }
    }
  }
}

// Round 6
// 728.756 us; speedup vs baseline: 24.6210x; 1.2194x over previous
//
#include <hip/hip_runtime.h>
#include <hip/hip_bf16.h>
#include <cstddef>
#include <cstdint>

#define TOT_ANCH 25200

typedef __bf16 bf16x8 __attribute__((ext_vector_type(8)));
typedef float f32x4 __attribute__((ext_vector_type(4)));

__device__ __forceinline__ float sig_(float x) { return 1.0f / (1.0f + __expf(-x)); }

__device__ __forceinline__ short f2bf(float v) {
  return (short)__builtin_bit_cast(unsigned short, __float2bfloat16(v));
}
__device__ __forceinline__ float bf2f(short v) {
  unsigned int u = ((unsigned int)(unsigned short)v) << 16;
  return __builtin_bit_cast(float, u);
}
__device__ __forceinline__ bf16x8 as_bf16x8(int4 v) { return __builtin_bit_cast(bf16x8, v); }

__device__ __forceinline__ void gload_lds16(const void* g, void* l) {
  __builtin_amdgcn_global_load_lds((const __attribute__((address_space(1))) void*)g,
                                   (__attribute__((address_space(3))) void*)l, 16, 0, 0);
}

// anchors[level][a][2]
__device__ const float d_anch[3][3][2] = {
    {{10.f, 13.f}, {16.f, 30.f}, {33.f, 23.f}},
    {{30.f, 61.f}, {62.f, 45.f}, {59.f, 119.f}},
    {{116.f, 90.f}, {156.f, 198.f}, {373.f, 326.f}}};

// ---------------------------------------------------------------------------
// f32 NCHW -> bf16 NHWC, LDS 32x32 tile, coalesced both sides. (r4-proven)
// grid: (ceil(HW/32), C/32, Bg), block 256.
// ---------------------------------------------------------------------------
__global__ __launch_bounds__(256) void to_nhwc_tile(const float* __restrict__ f,
                                                    short* __restrict__ fb, int C, int HW) {
  __shared__ short tile[32][33];
  const int p0 = blockIdx.x * 32, c0 = blockIdx.y * 32, b = blockIdx.z;
  const int t = threadIdx.x;
  {
    int cl = t >> 3, pl = (t & 7) * 4;
    int pr = p0 + pl;
    if (pr > HW - 4) pr = HW - 4;  // clamp: stays %4==0, dup data handled below
    const float4 v = *(const float4*)(f + ((long)b * C + c0 + cl) * HW + pr);
    tile[cl][pl + 0] = f2bf(v.x);
    tile[cl][pl + 1] = f2bf(v.y);
    tile[cl][pl + 2] = f2bf(v.z);
    tile[cl][pl + 3] = f2bf(v.w);
  }
  __syncthreads();
  {
    int pl = t >> 3, cl = (t & 7) * 4;
    int pp = p0 + pl;
    if (pp < HW) {
      // groups of 4 were written starting at min(p0+4k, HW-4)
      int k = pl >> 2;
      int start = p0 + 4 * k;
      if (start > HW - 4) start = HW - 4;
      int col = (start - p0) + (pp - start);
      short4 o;
      o.x = tile[cl + 0][col];
      o.y = tile[cl + 1][col];
      o.z = tile[cl + 2][col];
      o.w = tile[cl + 3][col];
      *(short4*)(fb + ((long)b * HW + pp) * C + c0 + cl) = o;
    }
  }
}

// ---------------------------------------------------------------------------
// w[o][i][3][3] f32 (OIHW) -> wt[t][off0/C + o][i] bf16, t-stride MC elems.
// Fused mode: called twice (off0 = 0 and C*C) into a [9][2C][C] buffer.
// ---------------------------------------------------------------------------
__global__ void wt_tf(const float* __restrict__ w, short* __restrict__ wt, long CC,
                      long MC, long off0) {
  long oi = (long)blockIdx.x * blockDim.x + threadIdx.x;
  if (oi >= CC) return;
#pragma unroll
  for (int t = 0; t < 9; ++t) wt[t * MC + off0 + oi] = f2bf(w[oi * 9 + t]);
}

// ---------------------------------------------------------------------------
// Implicit-GEMM conv3x3 (pad 1) via mfma_f32_16x16x32_bf16, BOTH branches
// fused on the M axis (M2 = nb_m*128; fused = 2C, fallback = C).
//   h[M2 x N] = sum_t wt[t] (M2 x C) * Xshift_t (C x N), + bias.
// kb OUTER, tap INNER: per kb the 9 shifted X tiles are read back-to-back ->
// L2-resident re-reads. 1D grid, XCD-chunked bijective swizzle; fastest grid
// axis selectable (m-fastest when fb dominates, n-fastest when wt dominates).
// 128x128 tile, BK=64, 4 waves (2x2) x (4x4) 16x16x32 fragments,
// global_load_lds width-16, XOR chunk swizzle via pre-swizzled global source.
// ---------------------------------------------------------------------------
__global__ __launch_bounds__(256) void conv3x3_mfma(
    const short* __restrict__ fb, const short* __restrict__ wt,
    const float* __restrict__ biasA, const float* __restrict__ biasB,
    short* __restrict__ h, const short* __restrict__ zbuf,
    int C, int H, int W, int HW, int nb_m, int nwg, int mfast) {
  __shared__ __align__(16) short As[128 * 64];
  __shared__ __align__(16) short Xs[128 * 64];

  // --- bijective XCD chunk swizzle (nwg % 8 == 0 in all our launches) ---
  const int orig = blockIdx.x;
  const int q = nwg >> 3, rr = nwg & 7;
  const int xcd = orig & 7;
  const int wg = (xcd < rr ? xcd * (q + 1) : rr * (q + 1) + (xcd - rr) * q) + (orig >> 3);
  int m, n;
  if (mfast) { m = wg % nb_m; n = wg / nb_m; }
  else       { const int nb_n = nwg / nb_m; n = wg % nb_n; m = wg / nb_n; }
  const int mt0 = m * 128;
  const int nt0 = n * 128;
  const int M2 = nb_m * 128;

  const int tid = threadIdx.x;
  const int lane = tid & 63;
  const int wave = tid >> 6;
  const int wm = (wave >> 1) * 64;
  const int wn = (wave & 1) * 64;
  const int s = tid & 7;

  int xs_x[4], xs_y[4];
  int xs_base[4];
  int as_base[4];
#pragma unroll
  for (int r = 0; r < 4; ++r) {
    int cl = r * 32 + (tid >> 3);
    int nn = nt0 + cl;
    int b = nn / HW; int p = nn - b * HW;
    int y = p / W;  int x = p - y * W;
    xs_x[r] = x; xs_y[r] = y;
    int swz = (s ^ (cl & 7)) * 8;
    xs_base[r] = ((b * H + y) * W + x) * C + swz;
    as_base[r] = (mt0 + cl) * C + swz;
  }

  f32x4 acc[4][4];
#pragma unroll
  for (int a_ = 0; a_ < 4; ++a_)
#pragma unroll
    for (int b_ = 0; b_ < 4; ++b_) acc[a_][b_] = (f32x4){0.f, 0.f, 0.f, 0.f};

  const int nkb = C >> 6;
  const long MC = (long)M2 * C;
  const short* gzb = zbuf + s * 8;

  for (int kb = 0; kb < nkb; ++kb) {
    const int kb64 = kb << 6;
    for (int t = 0; t < 9; ++t) {
      const int dy = t / 3 - 1, dx = t - (t / 3) * 3 - 1;
      const int doff = (dy * W + dx) * C + kb64;
      const short* gap = wt + (long)t * MC + kb64;
#pragma unroll
      for (int r = 0; r < 4; ++r) {
        gload_lds16(gap + as_base[r], (char*)As + r * 4096 + tid * 16);
        bool ok = ((unsigned)(xs_y[r] + dy) < (unsigned)H) &
                  ((unsigned)(xs_x[r] + dx) < (unsigned)W);
        const short* gx = ok ? fb + xs_base[r] + doff : gzb;
        gload_lds16(gx, (char*)Xs + r * 4096 + tid * 16);
      }
      __syncthreads();

#pragma unroll
      for (int ks = 0; ks < 2; ++ks) {
        bf16x8 af[4], xf[4];
#pragma unroll
        for (int mf = 0; mf < 4; ++mf) {
          int row = wm + mf * 16 + (lane & 15);
          int c = (ks * 4 + (lane >> 4)) ^ (row & 7);
          af[mf] = as_bf16x8(*(const int4*)((const char*)As + row * 128 + c * 16));
        }
#pragma unroll
        for (int nf = 0; nf < 4; ++nf) {
          int col = wn + nf * 16 + (lane & 15);
          int c = (ks * 4 + (lane >> 4)) ^ (col & 7);
          xf[nf] = as_bf16x8(*(const int4*)((const char*)Xs + col * 128 + c * 16));
        }
#pragma unroll
        for (int mf = 0; mf < 4; ++mf)
#pragma unroll
          for (int nf = 0; nf < 4; ++nf)
            acc[mf][nf] = __builtin_amdgcn_mfma_f32_16x16x32_bf16(af[mf], xf[nf],
                                                                  acc[mf][nf], 0, 0, 0);
      }
      __syncthreads();
    }
  }

  // epilogue: + bias (rows < C from biasA, rows >= C from biasB), bf16 NCHW
  int nb[4], np[4];
#pragma unroll
  for (int nf = 0; nf < 4; ++nf) {
    int nn = nt0 + wn + nf * 16 + (lane & 15);
    nb[nf] = nn / HW;
    np[nf] = nn - nb[nf] * HW;
  }
#pragma unroll
  for (int mf = 0; mf < 4; ++mf) {
    int co0 = mt0 + wm + mf * 16 + (lane >> 4) * 4;
#pragma unroll
    for (int rg = 0; rg < 4; ++rg) {
      int co = co0 + rg;
      float bv = co < C ? biasA[co] : biasB[co - C];
#pragma unroll
      for (int nf = 0; nf < 4; ++nf) {
        float v = acc[mf][nf][rg] + bv;
        h[((long)nb[nf] * M2 + co) * HW + np[nf]] = f2bf(v);
      }
    }
  }
}

// ---------------------------------------------------------------------------
// decode v2 (r4-proven): LDS-tiled 1x1 conv (C->NOUT) + bias + decode.
// Ct = batch-plane channel stride (2C fused, C unfused); h pre-offset for
// the 3D branch. grid: (ceil(HW/32), Bg).
// ---------------------------------------------------------------------------
template <int NOUT>
__global__ __launch_bounds__(256) void decode_v2(
    const short* __restrict__ h, const float* __restrict__ wb,
    const float* __restrict__ bb, float* __restrict__ out,
    int C, int Ct, int H, int W, int b0, int loff, float stride_, int lvl) {
  __shared__ float htile[32][33];
  __shared__ float wtileT[32][32];
  __shared__ float otile[32][NOUT + 1];
  const int HW = H * W;
  const int t = threadIdx.x;
  const int p0 = blockIdx.x * 32;
  const int bl = blockIdx.y;
  const int px = t & 31, og = t >> 5;

  float acc[4] = {0.f, 0.f, 0.f, 0.f};
  const int nch = C >> 5;
  for (int ch = 0; ch < nch; ++ch) {
    const int c0 = ch << 5;
    {
      int cl = t >> 3, pl = (t & 7) * 4;
      int pr = p0 + pl;
      if (pr > HW - 4) pr = HW - 4;  // clamp; dup columns belong to dead px
      const short4 v = *(const short4*)(h + ((long)bl * Ct + c0 + cl) * HW + pr);
      htile[cl][pl + 0] = bf2f(v.x);
      htile[cl][pl + 1] = bf2f(v.y);
      htile[cl][pl + 2] = bf2f(v.z);
      htile[cl][pl + 3] = bf2f(v.w);
    }
    {
      int j = t >> 3, cl = (t & 7) * 4;
      if (j < NOUT) {
        const float4 v = *(const float4*)(wb + (long)j * C + c0 + cl);
        wtileT[cl + 0][j] = v.x;
        wtileT[cl + 1][j] = v.y;
        wtileT[cl + 2][j] = v.z;
        wtileT[cl + 3][j] = v.w;
      } else {
        wtileT[cl + 0][j] = 0.f;
        wtileT[cl + 1][j] = 0.f;
        wtileT[cl + 2][j] = 0.f;
        wtileT[cl + 3][j] = 0.f;
      }
    }
    __syncthreads();
#pragma unroll
    for (int c = 0; c < 32; ++c) {
      float v = htile[c][px];
      const float4 wv = *(const float4*)&wtileT[c][og * 4];
      acc[0] = fmaf(v, wv.x, acc[0]);
      acc[1] = fmaf(v, wv.y, acc[1]);
      acc[2] = fmaf(v, wv.z, acc[2]);
      acc[3] = fmaf(v, wv.w, acc[3]);
    }
    __syncthreads();
  }
#pragma unroll
  for (int g = 0; g < 4; ++g) {
    int j = og * 4 + g;
    if (j < NOUT) otile[px][j] = acc[g] + bb[j];
  }
  __syncthreads();

  if (t < 96) {
    const int pxx = t / 3, a = t - (t / 3) * 3;
    const int p = p0 + pxx;
    if (p < HW) {
      float* o = out + ((size_t)(b0 + bl) * TOT_ANCH + loff + (size_t)a * HW + p) * 17;
      if (NOUT == 24) {
        const int y = p / W, x = p - (p / W) * W;
        float s0 = sig_(otile[pxx][a * 8 + 0]);
        float s1 = sig_(otile[pxx][a * 8 + 1]);
        float sw = sig_(otile[pxx][a * 8 + 2]) * 2.f;
        float sh = sig_(otile[pxx][a * 8 + 3]) * 2.f;
        o[0] = (s0 * 2.f - 0.5f + (float)x) * stride_;
        o[1] = (s1 * 2.f - 0.5f + (float)y) * stride_;
        o[2] = sw * sw * d_anch[lvl][a][0];
        o[3] = sh * sh * d_anch[lvl][a][1];
        o[4] = sig_(otile[pxx][a * 8 + 4]);
        o[5] = sig_(otile[pxx][a * 8 + 5]);
        o[6] = sig_(otile[pxx][a * 8 + 6]);
        o[7] = sig_(otile[pxx][a * 8 + 7]);
      } else {
        float v0 = otile[pxx][a * 9 + 0], v1 = otile[pxx][a * 9 + 1];
        float v2 = otile[pxx][a * 9 + 2], v3 = otile[pxx][a * 9 + 3];
        float v4 = otile[pxx][a * 9 + 4], v5 = otile[pxx][a * 9 + 5];
        float v6 = otile[pxx][a * 9 + 6], v7 = otile[pxx][a * 9 + 7];
        float v8 = otile[pxx][a * 9 + 8];
        float n0 = fmaxf(sqrtf(v2 * v2 + v3 * v3), 1e-12f);
        float n1 = fmaxf(sqrtf(v4 * v4 + v5 * v5), 1e-12f);
        o[8] = v0;
        o[9] = v1;
        o[10] = v2 / n0;
        o[11] = v3 / n0;
        o[12] = v4 / n1;
        o[13] = v5 / n1;
        o[14] = sig_(v6) * 2.f - 1.f;
        o[15] = sig_(v7) * 2.f - 1.f;
        o[16] = sig_(v8) * 2.f - 1.f;
      }
    }
  }
}

// ---------------------------------------------------------------------------

static inline size_t al256(size_t x) { return (x + 255) & ~(size_t)255; }

extern "C" void kernel_launch(void* const* d_in, const int* in_sizes, int n_in,
                              void* d_out, int out_size, void* d_ws, size_t ws_size,
                              hipStream_t stream) {
  (void)in_sizes; (void)n_in; (void)out_size;
  char* ws = (char*)d_ws;
  float* out = (float*)d_out;

  hipMemsetAsync(ws, 0, 256, stream);  // zero page for OOB tap columns

  struct Lvl { int C, H, W, loff; float stride; };
  const Lvl L[3] = {{256, 80, 80, 0, 8.f}, {512, 40, 40, 19200, 16.f},
                    {1024, 20, 20, 24000, 32.f}};
  const int B = 8;

  for (int i = 0; i < 3; ++i) {
    const float* f   = (const float*)d_in[9 * i + 0];
    const float* w2a = (const float*)d_in[9 * i + 1];
    const float* b2a = (const float*)d_in[9 * i + 2];
    const float* w2b = (const float*)d_in[9 * i + 3];
    const float* b2b = (const float*)d_in[9 * i + 4];
    const float* w3a = (const float*)d_in[9 * i + 5];
    const float* b3a = (const float*)d_in[9 * i + 6];
    const float* w3b = (const float*)d_in[9 * i + 7];
    const float* b3b = (const float*)d_in[9 * i + 8];

    const int C = L[i].C, H = L[i].H, W = L[i].W, HW = H * W;
    const long CC = (long)C * C;
    const int ptiles = (HW + 31) / 32;
    const int wtf_blocks = (int)((CC + 255) / 256);
    // m-fastest when fb bytes dominate wt bytes (L0/L1), else n-fastest (L2)
    const int mfast = ((size_t)B * HW * C >= (size_t)18 * CC) ? 1 : 0;

    // --- fused (both branches, M = 2C): find a batch split that fits ws ---
    // fused wt buffer: 9 taps * 2C * C bf16 = 36*CC BYTES (r5 bug: was 18*CC)
    int nbg = 0;
    for (int cand = 1; cand <= 8; cand <<= 1) {
      int Bg = B / cand;
      if (((long)Bg * HW) % 128) continue;  // conv needs Ng % 128 == 0
      size_t need = 256 + al256((size_t)Bg * HW * C * 2) + al256((size_t)36 * CC) +
                    (size_t)Bg * 2 * C * HW * 2;
      if (need <= ws_size) { nbg = cand; break; }
    }

    if (nbg) {
      const int Bg = B / nbg;
      size_t fb_off = 256;
      size_t wt_off = fb_off + al256((size_t)Bg * HW * C * 2);
      size_t h_off  = wt_off + al256((size_t)36 * CC);
      short* fb  = (short*)(ws + fb_off);
      short* wtb = (short*)(ws + wt_off);
      short* hb  = (short*)(ws + h_off);
      const short* zb = (const short*)ws;

      wt_tf<<<wtf_blocks, 256, 0, stream>>>(w2a, wtb, CC, 2 * CC, 0);
      wt_tf<<<wtf_blocks, 256, 0, stream>>>(w3a, wtb, CC, 2 * CC, CC);

      const int nb_m = (2 * C) / 128;
      for (int g = 0; g < nbg; ++g) {
        const int b0 = g * Bg;
        to_nhwc_tile<<<dim3(ptiles, C / 32, Bg), 256, 0, stream>>>(
            f + (size_t)b0 * C * HW, fb, C, HW);
        const int Ng = Bg * HW;
        const int nwg = (Ng / 128) * nb_m;
        conv3x3_mfma<<<nwg, 256, 0, stream>>>(fb, wtb, b2a, b3a, hb, zb, C, H, W, HW,
                                              nb_m, nwg, mfast);
        decode_v2<24><<<dim3(ptiles, Bg), 256, 0, stream>>>(
            hb, w2b, b2b, out, C, 2 * C, H, W, b0, L[i].loff, L[i].stride, i);
        decode_v2<27><<<dim3(ptiles, Bg), 256, 0, stream>>>(
            hb + (size_t)C * HW, w3b, b3b, out, C, 2 * C, H, W, b0, L[i].loff,
            L[i].stride, i);
      }
    } else {
      // --- unfused fallback (r4 footprint): M = C, one branch at a time ---
      int nbg2 = 0;
      for (int cand = 1; cand <= 8; cand <<= 1) {
        int Bg = B / cand;
        if (((long)Bg * HW) % 128) continue;
        size_t need = 256 + al256((size_t)Bg * HW * C * 2) + al256((size_t)9 * CC * 2) +
                      (size_t)Bg * C * HW * 2;
        if (need <= ws_size) { nbg2 = cand; break; }
      }
      if (!nbg2) nbg2 = 1;  // should not happen (38.5 MB floor proven in r2-r4)
      const int Bg = B / nbg2;
      size_t fb_off = 256;
      size_t wt_off = fb_off + al256((size_t)Bg * HW * C * 2);
      size_t h_off  = wt_off + al256((size_t)9 * CC * 2);
      short* fb  = (short*)(ws + fb_off);
      short* wtb = (short*)(ws + wt_off);
      short* hb  = (short*)(ws + h_off);
      const short* zb = (const short*)ws;
      const int nb_m = C / 128;

      for (int br = 0; br < 2; ++br) {
        const float* wa = br ? w3a : w2a;
        const float* ba = br ? b3a : b2a;
        wt_tf<<<wtf_blocks, 256, 0, stream>>>(wa, wtb, CC, CC, 0);
        for (int g = 0; g < nbg2; ++g) {
          const int b0 = g * Bg;
          to_nhwc_tile<<<dim3(ptiles, C / 32, Bg), 256, 0, stream>>>(
              f + (size_t)b0 * C * HW, fb, C, HW);
          const int Ng = Bg * HW;
          const int nwg = (Ng / 128) * nb_m;
          conv3x3_mfma<<<nwg, 256, 0, stream>>>(fb, wtb, ba, ba, hb, zb, C, H, W, HW,
                                                nb_m, nwg, mfast);
          if (br == 0) {
            decode_v2<24><<<dim3(ptiles, Bg), 256, 0, stream>>>(
                hb, w2b, b2b, out, C, C, H, W, b0, L[i].loff, L[i].stride, i);
          } else {
            decode_v2<27><<<dim3(ptiles, Bg), 256, 0, stream>>>(
                hb, w3b, b3b, out, C, C, H, W, b0, L[i].loff, L[i].stride, i);
          }
        }
      }
    }
  }
}

// Round 7
// 720.892 us; speedup vs baseline: 24.8895x; 1.0109x over previous
//
#include <hip/hip_runtime.h>
#include <hip/hip_bf16.h>
#include <cstddef>
#include <cstdint>

#define TOT_ANCH 25200

typedef __bf16 bf16x8 __attribute__((ext_vector_type(8)));
typedef float f32x4 __attribute__((ext_vector_type(4)));

__device__ __forceinline__ float sig_(float x) { return 1.0f / (1.0f + __expf(-x)); }

__device__ __forceinline__ short f2bf(float v) {
  return (short)__builtin_bit_cast(unsigned short, __float2bfloat16(v));
}
__device__ __forceinline__ float bf2f(short v) {
  unsigned int u = ((unsigned int)(unsigned short)v) << 16;
  return __builtin_bit_cast(float, u);
}
__device__ __forceinline__ bf16x8 as_bf16x8(int4 v) { return __builtin_bit_cast(bf16x8, v); }

__device__ __forceinline__ void gload_lds16(const void* g, void* l) {
  __builtin_amdgcn_global_load_lds((const __attribute__((address_space(1))) void*)g,
                                   (__attribute__((address_space(3))) void*)l, 16, 0, 0);
}

// anchors[level][a][2]
__device__ const float d_anch[3][3][2] = {
    {{10.f, 13.f}, {16.f, 30.f}, {33.f, 23.f}},
    {{30.f, 61.f}, {62.f, 45.f}, {59.f, 119.f}},
    {{116.f, 90.f}, {156.f, 198.f}, {373.f, 326.f}}};

// ---------------------------------------------------------------------------
// f32 NCHW -> bf16 NHWC, LDS 32x32 tile, coalesced both sides. (r4-proven)
// grid: (ceil(HW/32), C/32, Bg), block 256.
// ---------------------------------------------------------------------------
__global__ __launch_bounds__(256) void to_nhwc_tile(const float* __restrict__ f,
                                                    short* __restrict__ fb, int C, int HW) {
  __shared__ short tile[32][33];
  const int p0 = blockIdx.x * 32, c0 = blockIdx.y * 32, b = blockIdx.z;
  const int t = threadIdx.x;
  {
    int cl = t >> 3, pl = (t & 7) * 4;
    int pr = p0 + pl;
    if (pr > HW - 4) pr = HW - 4;  // clamp: stays %4==0, dup data handled below
    const float4 v = *(const float4*)(f + ((long)b * C + c0 + cl) * HW + pr);
    tile[cl][pl + 0] = f2bf(v.x);
    tile[cl][pl + 1] = f2bf(v.y);
    tile[cl][pl + 2] = f2bf(v.z);
    tile[cl][pl + 3] = f2bf(v.w);
  }
  __syncthreads();
  {
    int pl = t >> 3, cl = (t & 7) * 4;
    int pp = p0 + pl;
    if (pp < HW) {
      // groups of 4 were written starting at min(p0+4k, HW-4)
      int k = pl >> 2;
      int start = p0 + 4 * k;
      if (start > HW - 4) start = HW - 4;
      int col = (start - p0) + (pp - start);
      short4 o;
      o.x = tile[cl + 0][col];
      o.y = tile[cl + 1][col];
      o.z = tile[cl + 2][col];
      o.w = tile[cl + 3][col];
      *(short4*)(fb + ((long)b * HW + pp) * C + c0 + cl) = o;
    }
  }
}

// ---------------------------------------------------------------------------
// w[o][i][3][3] f32 (OIHW) -> wt[t][off0/C + o][i] bf16, t-stride MC elems.
// Fused mode: called twice (off0 = 0 and C*C) into a [9][2C][C] buffer.
// ---------------------------------------------------------------------------
__global__ void wt_tf(const float* __restrict__ w, short* __restrict__ wt, long CC,
                      long MC, long off0) {
  long oi = (long)blockIdx.x * blockDim.x + threadIdx.x;
  if (oi >= CC) return;
#pragma unroll
  for (int t = 0; t < 9; ++t) wt[t * MC + off0 + oi] = f2bf(w[oi * 9 + t]);
}

// ---------------------------------------------------------------------------
// Implicit-GEMM conv3x3 (pad 1) via mfma_f32_16x16x32_bf16, branches fused on
// M (M2 = nb_m*128). kb OUTER, tap INNER (flat step = kb*9 + t).
// r7: DOUBLE-BUFFERED issue-early staging (T3-minimum): stage step+1 into
// LDS half B while computing step from half A; ONE barrier per step. The
// compiler's vmcnt(0)-before-barrier drain is cheap because the prefetch had
// the whole MFMA phase to land. s_setprio(1) around the MFMA cluster (T5).
// LDS 2 x (16+16) KB = 64 KB -> 2 blocks/CU cap (measured residency was 1.4).
// ---------------------------------------------------------------------------
__global__ __launch_bounds__(256) void conv3x3_mfma(
    const short* __restrict__ fb, const short* __restrict__ wt,
    const float* __restrict__ biasA, const float* __restrict__ biasB,
    short* __restrict__ h, const short* __restrict__ zbuf,
    int C, int H, int W, int HW, int nb_m, int nwg, int mfast) {
  __shared__ __align__(16) short As[2][128 * 64];
  __shared__ __align__(16) short Xs[2][128 * 64];

  // --- bijective XCD chunk swizzle (nwg % 8 == 0 in all our launches) ---
  const int orig = blockIdx.x;
  const int q = nwg >> 3, rr = nwg & 7;
  const int xcd = orig & 7;
  const int wg = (xcd < rr ? xcd * (q + 1) : rr * (q + 1) + (xcd - rr) * q) + (orig >> 3);
  int m, n;
  if (mfast) { m = wg % nb_m; n = wg / nb_m; }
  else       { const int nb_n = nwg / nb_m; n = wg % nb_n; m = wg / nb_n; }
  const int mt0 = m * 128;
  const int nt0 = n * 128;
  const int M2 = nb_m * 128;

  const int tid = threadIdx.x;
  const int lane = tid & 63;
  const int wave = tid >> 6;
  const int wm = (wave >> 1) * 64;
  const int wn = (wave & 1) * 64;
  const int s = tid & 7;

  int xs_x[4], xs_y[4];
  int xs_base[4];
  int as_base[4];
#pragma unroll
  for (int r = 0; r < 4; ++r) {
    int cl = r * 32 + (tid >> 3);
    int nn = nt0 + cl;
    int b = nn / HW; int p = nn - b * HW;
    int y = p / W;  int x = p - y * W;
    xs_x[r] = x; xs_y[r] = y;
    int swz = (s ^ (cl & 7)) * 8;
    xs_base[r] = ((b * H + y) * W + x) * C + swz;
    as_base[r] = (mt0 + cl) * C + swz;
  }

  f32x4 acc[4][4];
#pragma unroll
  for (int a_ = 0; a_ < 4; ++a_)
#pragma unroll
    for (int b_ = 0; b_ < 4; ++b_) acc[a_][b_] = (f32x4){0.f, 0.f, 0.f, 0.f};

  const int nkb = C >> 6;
  const int nsteps = nkb * 9;
  const long MC = (long)M2 * C;
  const short* gzb = zbuf + s * 8;

  // stage (kb64, tap t) into LDS half `half`
  auto STAGE = [&](int kb64, int t, int half) {
    const int tdiv3 = t / 3;
    const int dy = tdiv3 - 1, dx = t - tdiv3 * 3 - 1;
    const int doff = (dy * W + dx) * C + kb64;
    const short* gap = wt + (long)t * MC + kb64;
    char* Ah = (char*)(&As[half][0]);
    char* Xh = (char*)(&Xs[half][0]);
#pragma unroll
    for (int r = 0; r < 4; ++r) {
      gload_lds16(gap + as_base[r], Ah + r * 4096 + tid * 16);
      bool ok = ((unsigned)(xs_y[r] + dy) < (unsigned)H) &
                ((unsigned)(xs_x[r] + dx) < (unsigned)W);
      const short* gx = ok ? fb + xs_base[r] + doff : gzb;
      gload_lds16(gx, Xh + r * 4096 + tid * 16);
    }
  };

  STAGE(0, 0, 0);
  __syncthreads();  // drain prologue stage

  int ntt = 1, nkb64 = 0;  // (tap, kb*64) of step+1
  for (int step = 0; step < nsteps; ++step) {
    if (step + 1 < nsteps) {
      STAGE(nkb64, ntt, (step + 1) & 1);  // in flight across the MFMA phase
      if (++ntt == 9) { ntt = 0; nkb64 += 64; }
    }
    const char* Ac = (const char*)(&As[step & 1][0]);
    const char* Xc = (const char*)(&Xs[step & 1][0]);
#pragma unroll
    for (int ks = 0; ks < 2; ++ks) {
      bf16x8 af[4], xf[4];
#pragma unroll
      for (int mf = 0; mf < 4; ++mf) {
        int row = wm + mf * 16 + (lane & 15);
        int c = (ks * 4 + (lane >> 4)) ^ (row & 7);
        af[mf] = as_bf16x8(*(const int4*)(Ac + row * 128 + c * 16));
      }
#pragma unroll
      for (int nf = 0; nf < 4; ++nf) {
        int col = wn + nf * 16 + (lane & 15);
        int c = (ks * 4 + (lane >> 4)) ^ (col & 7);
        xf[nf] = as_bf16x8(*(const int4*)(Xc + col * 128 + c * 16));
      }
      __builtin_amdgcn_s_setprio(1);
#pragma unroll
      for (int mf = 0; mf < 4; ++mf)
#pragma unroll
        for (int nf = 0; nf < 4; ++nf)
          acc[mf][nf] = __builtin_amdgcn_mfma_f32_16x16x32_bf16(af[mf], xf[nf],
                                                                acc[mf][nf], 0, 0, 0);
      __builtin_amdgcn_s_setprio(0);
    }
    __syncthreads();  // all waves done reading half (step&1); stage(step+1) drained
  }

  // epilogue: + bias (rows < C from biasA, rows >= C from biasB), bf16 NCHW
  int nb[4], np[4];
#pragma unroll
  for (int nf = 0; nf < 4; ++nf) {
    int nn = nt0 + wn + nf * 16 + (lane & 15);
    nb[nf] = nn / HW;
    np[nf] = nn - nb[nf] * HW;
  }
#pragma unroll
  for (int mf = 0; mf < 4; ++mf) {
    int co0 = mt0 + wm + mf * 16 + (lane >> 4) * 4;
#pragma unroll
    for (int rg = 0; rg < 4; ++rg) {
      int co = co0 + rg;
      float bv = co < C ? biasA[co] : biasB[co - C];
#pragma unroll
      for (int nf = 0; nf < 4; ++nf) {
        float v = acc[mf][nf][rg] + bv;
        h[((long)nb[nf] * M2 + co) * HW + np[nf]] = f2bf(v);
      }
    }
  }
}

// ---------------------------------------------------------------------------
// decode v2 (r4-proven): LDS-tiled 1x1 conv (C->NOUT) + bias + decode.
// Ct = batch-plane channel stride (2C fused, C unfused); h pre-offset for
// the 3D branch. grid: (ceil(HW/32), Bg).
// ---------------------------------------------------------------------------
template <int NOUT>
__global__ __launch_bounds__(256) void decode_v2(
    const short* __restrict__ h, const float* __restrict__ wb,
    const float* __restrict__ bb, float* __restrict__ out,
    int C, int Ct, int H, int W, int b0, int loff, float stride_, int lvl) {
  __shared__ float htile[32][33];
  __shared__ float wtileT[32][32];
  __shared__ float otile[32][NOUT + 1];
  const int HW = H * W;
  const int t = threadIdx.x;
  const int p0 = blockIdx.x * 32;
  const int bl = blockIdx.y;
  const int px = t & 31, og = t >> 5;

  float acc[4] = {0.f, 0.f, 0.f, 0.f};
  const int nch = C >> 5;
  for (int ch = 0; ch < nch; ++ch) {
    const int c0 = ch << 5;
    {
      int cl = t >> 3, pl = (t & 7) * 4;
      int pr = p0 + pl;
      if (pr > HW - 4) pr = HW - 4;  // clamp; dup columns belong to dead px
      const short4 v = *(const short4*)(h + ((long)bl * Ct + c0 + cl) * HW + pr);
      htile[cl][pl + 0] = bf2f(v.x);
      htile[cl][pl + 1] = bf2f(v.y);
      htile[cl][pl + 2] = bf2f(v.z);
      htile[cl][pl + 3] = bf2f(v.w);
    }
    {
      int j = t >> 3, cl = (t & 7) * 4;
      if (j < NOUT) {
        const float4 v = *(const float4*)(wb + (long)j * C + c0 + cl);
        wtileT[cl + 0][j] = v.x;
        wtileT[cl + 1][j] = v.y;
        wtileT[cl + 2][j] = v.z;
        wtileT[cl + 3][j] = v.w;
      } else {
        wtileT[cl + 0][j] = 0.f;
        wtileT[cl + 1][j] = 0.f;
        wtileT[cl + 2][j] = 0.f;
        wtileT[cl + 3][j] = 0.f;
      }
    }
    __syncthreads();
#pragma unroll
    for (int c = 0; c < 32; ++c) {
      float v = htile[c][px];
      const float4 wv = *(const float4*)&wtileT[c][og * 4];
      acc[0] = fmaf(v, wv.x, acc[0]);
      acc[1] = fmaf(v, wv.y, acc[1]);
      acc[2] = fmaf(v, wv.z, acc[2]);
      acc[3] = fmaf(v, wv.w, acc[3]);
    }
    __syncthreads();
  }
#pragma unroll
  for (int g = 0; g < 4; ++g) {
    int j = og * 4 + g;
    if (j < NOUT) otile[px][j] = acc[g] + bb[j];
  }
  __syncthreads();

  if (t < 96) {
    const int pxx = t / 3, a = t - (t / 3) * 3;
    const int p = p0 + pxx;
    if (p < HW) {
      float* o = out + ((size_t)(b0 + bl) * TOT_ANCH + loff + (size_t)a * HW + p) * 17;
      if (NOUT == 24) {
        const int y = p / W, x = p - (p / W) * W;
        float s0 = sig_(otile[pxx][a * 8 + 0]);
        float s1 = sig_(otile[pxx][a * 8 + 1]);
        float sw = sig_(otile[pxx][a * 8 + 2]) * 2.f;
        float sh = sig_(otile[pxx][a * 8 + 3]) * 2.f;
        o[0] = (s0 * 2.f - 0.5f + (float)x) * stride_;
        o[1] = (s1 * 2.f - 0.5f + (float)y) * stride_;
        o[2] = sw * sw * d_anch[lvl][a][0];
        o[3] = sh * sh * d_anch[lvl][a][1];
        o[4] = sig_(otile[pxx][a * 8 + 4]);
        o[5] = sig_(otile[pxx][a * 8 + 5]);
        o[6] = sig_(otile[pxx][a * 8 + 6]);
        o[7] = sig_(otile[pxx][a * 8 + 7]);
      } else {
        float v0 = otile[pxx][a * 9 + 0], v1 = otile[pxx][a * 9 + 1];
        float v2 = otile[pxx][a * 9 + 2], v3 = otile[pxx][a * 9 + 3];
        float v4 = otile[pxx][a * 9 + 4], v5 = otile[pxx][a * 9 + 5];
        float v6 = otile[pxx][a * 9 + 6], v7 = otile[pxx][a * 9 + 7];
        float v8 = otile[pxx][a * 9 + 8];
        float n0 = fmaxf(sqrtf(v2 * v2 + v3 * v3), 1e-12f);
        float n1 = fmaxf(sqrtf(v4 * v4 + v5 * v5), 1e-12f);
        o[8] = v0;
        o[9] = v1;
        o[10] = v2 / n0;
        o[11] = v3 / n0;
        o[12] = v4 / n1;
        o[13] = v5 / n1;
        o[14] = sig_(v6) * 2.f - 1.f;
        o[15] = sig_(v7) * 2.f - 1.f;
        o[16] = sig_(v8) * 2.f - 1.f;
      }
    }
  }
}

// ---------------------------------------------------------------------------

static inline size_t al256(size_t x) { return (x + 255) & ~(size_t)255; }

extern "C" void kernel_launch(void* const* d_in, const int* in_sizes, int n_in,
                              void* d_out, int out_size, void* d_ws, size_t ws_size,
                              hipStream_t stream) {
  (void)in_sizes; (void)n_in; (void)out_size;
  char* ws = (char*)d_ws;
  float* out = (float*)d_out;

  hipMemsetAsync(ws, 0, 256, stream);  // zero page for OOB tap columns

  struct Lvl { int C, H, W, loff; float stride; };
  const Lvl L[3] = {{256, 80, 80, 0, 8.f}, {512, 40, 40, 19200, 16.f},
                    {1024, 20, 20, 24000, 32.f}};
  const int B = 8;

  for (int i = 0; i < 3; ++i) {
    const float* f   = (const float*)d_in[9 * i + 0];
    const float* w2a = (const float*)d_in[9 * i + 1];
    const float* b2a = (const float*)d_in[9 * i + 2];
    const float* w2b = (const float*)d_in[9 * i + 3];
    const float* b2b = (const float*)d_in[9 * i + 4];
    const float* w3a = (const float*)d_in[9 * i + 5];
    const float* b3a = (const float*)d_in[9 * i + 6];
    const float* w3b = (const float*)d_in[9 * i + 7];
    const float* b3b = (const float*)d_in[9 * i + 8];

    const int C = L[i].C, H = L[i].H, W = L[i].W, HW = H * W;
    const long CC = (long)C * C;
    const int ptiles = (HW + 31) / 32;
    const int wtf_blocks = (int)((CC + 255) / 256);
    // m-fastest when fb elems dominate wt elems (L0/L1), else n-fastest (L2)
    const int mfast = ((size_t)B * HW * C >= (size_t)18 * CC) ? 1 : 0;

    // --- fused (both branches, M = 2C): find a batch split that fits ws ---
    // fused wt buffer: 9 taps * 2C * C bf16 = 36*CC BYTES
    int nbg = 0;
    for (int cand = 1; cand <= 8; cand <<= 1) {
      int Bg = B / cand;
      if (((long)Bg * HW) % 128) continue;  // conv needs Ng % 128 == 0
      size_t need = 256 + al256((size_t)Bg * HW * C * 2) + al256((size_t)36 * CC) +
                    (size_t)Bg * 2 * C * HW * 2;
      if (need <= ws_size) { nbg = cand; break; }
    }

    if (nbg) {
      const int Bg = B / nbg;
      size_t fb_off = 256;
      size_t wt_off = fb_off + al256((size_t)Bg * HW * C * 2);
      size_t h_off  = wt_off + al256((size_t)36 * CC);
      short* fb  = (short*)(ws + fb_off);
      short* wtb = (short*)(ws + wt_off);
      short* hb  = (short*)(ws + h_off);
      const short* zb = (const short*)ws;

      wt_tf<<<wtf_blocks, 256, 0, stream>>>(w2a, wtb, CC, 2 * CC, 0);
      wt_tf<<<wtf_blocks, 256, 0, stream>>>(w3a, wtb, CC, 2 * CC, CC);

      const int nb_m = (2 * C) / 128;
      for (int g = 0; g < nbg; ++g) {
        const int b0 = g * Bg;
        to_nhwc_tile<<<dim3(ptiles, C / 32, Bg), 256, 0, stream>>>(
            f + (size_t)b0 * C * HW, fb, C, HW);
        const int Ng = Bg * HW;
        const int nwg = (Ng / 128) * nb_m;
        conv3x3_mfma<<<nwg, 256, 0, stream>>>(fb, wtb, b2a, b3a, hb, zb, C, H, W, HW,
                                              nb_m, nwg, mfast);
        decode_v2<24><<<dim3(ptiles, Bg), 256, 0, stream>>>(
            hb, w2b, b2b, out, C, 2 * C, H, W, b0, L[i].loff, L[i].stride, i);
        decode_v2<27><<<dim3(ptiles, Bg), 256, 0, stream>>>(
            hb + (size_t)C * HW, w3b, b3b, out, C, 2 * C, H, W, b0, L[i].loff,
            L[i].stride, i);
      }
    } else {
      // --- unfused fallback (r4 footprint): M = C, one branch at a time ---
      int nbg2 = 0;
      for (int cand = 1; cand <= 8; cand <<= 1) {
        int Bg = B / cand;
        if (((long)Bg * HW) % 128) continue;
        size_t need = 256 + al256((size_t)Bg * HW * C * 2) + al256((size_t)9 * CC * 2) +
                      (size_t)Bg * C * HW * 2;
        if (need <= ws_size) { nbg2 = cand; break; }
      }
      if (!nbg2) nbg2 = 1;  // should not happen (38.5 MB floor proven in r2-r4)
      const int Bg = B / nbg2;
      size_t fb_off = 256;
      size_t wt_off = fb_off + al256((size_t)Bg * HW * C * 2);
      size_t h_off  = wt_off + al256((size_t)9 * CC * 2);
      short* fb  = (short*)(ws + fb_off);
      short* wtb = (short*)(ws + wt_off);
      short* hb  = (short*)(ws + h_off);
      const short* zb = (const short*)ws;
      const int nb_m = C / 128;

      for (int br = 0; br < 2; ++br) {
        const float* wa = br ? w3a : w2a;
        const float* ba = br ? b3a : b2a;
        wt_tf<<<wtf_blocks, 256, 0, stream>>>(wa, wtb, CC, CC, 0);
        for (int g = 0; g < nbg2; ++g) {
          const int b0 = g * Bg;
          to_nhwc_tile<<<dim3(ptiles, C / 32, Bg), 256, 0, stream>>>(
              f + (size_t)b0 * C * HW, fb, C, HW);
          const int Ng = Bg * HW;
          const int nwg = (Ng / 128) * nb_m;
          conv3x3_mfma<<<nwg, 256, 0, stream>>>(fb, wtb, ba, ba, hb, zb, C, H, W, HW,
                                                nb_m, nwg, mfast);
          if (br == 0) {
            decode_v2<24><<<dim3(ptiles, Bg), 256, 0, stream>>>(
                hb, w2b, b2b, out, C, C, H, W, b0, L[i].loff, L[i].stride, i);
          } else {
            decode_v2<27><<<dim3(ptiles, Bg), 256, 0, stream>>>(
                hb, w3b, b3b, out, C, C, H, W, b0, L[i].loff, L[i].stride, i);
          }
        }
      }
    }
  }
}

// Round 8
// 555.819 us; speedup vs baseline: 32.2815x; 1.2970x over previous
//
#include <hip/hip_runtime.h>
#include <hip/hip_bf16.h>
#include <cstddef>
#include <cstdint>
#include <climits>

#define TOT_ANCH 25200

typedef __bf16 bf16x8 __attribute__((ext_vector_type(8)));
typedef float f32x4 __attribute__((ext_vector_type(4)));

__device__ __forceinline__ float sig_(float x) { return 1.0f / (1.0f + __expf(-x)); }

__device__ __forceinline__ short f2bf(float v) {
  return (short)__builtin_bit_cast(unsigned short, __float2bfloat16(v));
}
__device__ __forceinline__ float bf2f(short v) {
  unsigned int u = ((unsigned int)(unsigned short)v) << 16;
  return __builtin_bit_cast(float, u);
}
__device__ __forceinline__ bf16x8 as_bf16x8(int4 v) { return __builtin_bit_cast(bf16x8, v); }

__device__ __forceinline__ void gload_lds16(const void* g, void* l) {
  __builtin_amdgcn_global_load_lds((const __attribute__((address_space(1))) void*)g,
                                   (__attribute__((address_space(3))) void*)l, 16, 0, 0);
}

// anchors[level][a][2]
__device__ const float d_anch[3][3][2] = {
    {{10.f, 13.f}, {16.f, 30.f}, {33.f, 23.f}},
    {{30.f, 61.f}, {62.f, 45.f}, {59.f, 119.f}},
    {{116.f, 90.f}, {156.f, 198.f}, {373.f, 326.f}}};

// --------------------------- param structs (by value) -----------------------
struct TrP {  // f32 NCHW -> bf16 NHWC
  const float* f; short* fb; int C, HW, ptiles, c32, blk0;
};
struct WtP {  // OIHW 3x3 f32 -> [t][o][i] bf16 (off0 selects branch row block)
  const float* w; short* dst; long CC, MC, off0; int blk0;
};
struct ConvP {
  const short* fb; const short* wt; const float* bA; const float* bB; short* h;
  int C, H, W, HW, nb_m, nwg, mfast, blk0;
};
struct DeP {
  const short* h; const float* wb; const float* bb;
  int C, Ct, H, W, b0, loff, ptiles, lvl, blk0; float stride;
};

// ---------------------------------------------------------------------------
// Fused transpose: all levels in one launch; block -> level by blk0 range.
// ---------------------------------------------------------------------------
__global__ __launch_bounds__(256) void to_nhwc_mega(TrP T0, TrP T1, TrP T2) {
  __shared__ short tile[32][33];
  int bid = blockIdx.x;
  TrP T = bid >= T2.blk0 ? T2 : (bid >= T1.blk0 ? T1 : T0);
  int l = bid - T.blk0;
  const int pt = l % T.ptiles; l /= T.ptiles;
  const int cg = l % T.c32;
  const int b = l / T.c32;
  const int p0 = pt * 32, c0 = cg * 32, HW = T.HW, C = T.C;
  const int t = threadIdx.x;
  {
    int cl = t >> 3, pl = (t & 7) * 4;
    int pr = p0 + pl;
    if (pr > HW - 4) pr = HW - 4;  // clamp: stays %4==0, dup handled below
    const float4 v = *(const float4*)(T.f + ((long)b * C + c0 + cl) * HW + pr);
    tile[cl][pl + 0] = f2bf(v.x);
    tile[cl][pl + 1] = f2bf(v.y);
    tile[cl][pl + 2] = f2bf(v.z);
    tile[cl][pl + 3] = f2bf(v.w);
  }
  __syncthreads();
  {
    int pl = t >> 3, cl = (t & 7) * 4;
    int pp = p0 + pl;
    if (pp < HW) {
      int k = pl >> 2;
      int start = p0 + 4 * k;
      if (start > HW - 4) start = HW - 4;
      int col = (start - p0) + (pp - start);
      short4 o;
      o.x = tile[cl + 0][col];
      o.y = tile[cl + 1][col];
      o.z = tile[cl + 2][col];
      o.w = tile[cl + 3][col];
      *(short4*)(T.fb + ((long)b * HW + pp) * C + c0 + cl) = o;
    }
  }
}

// ---------------------------------------------------------------------------
// Fused weight transform: up to 6 jobs (3 levels x 2 branches) in one launch.
// ---------------------------------------------------------------------------
__global__ void wt_mega(WtP j0, WtP j1, WtP j2, WtP j3, WtP j4, WtP j5) {
  int bid = blockIdx.x;
  WtP J = bid >= j5.blk0 ? j5 : bid >= j4.blk0 ? j4 : bid >= j3.blk0 ? j3 :
          bid >= j2.blk0 ? j2 : bid >= j1.blk0 ? j1 : j0;
  long oi = (long)(bid - J.blk0) * 256 + threadIdx.x;
  if (oi >= J.CC) return;
#pragma unroll
  for (int t = 0; t < 9; ++t) J.dst[t * J.MC + J.off0 + oi] = f2bf(J.w[oi * 9 + t]);
}

// ---------------------------------------------------------------------------
// Implicit-GEMM conv3x3 (pad 1), branches fused on M (M2 = nb_m*128), ALL
// LEVELS in one launch (block -> level by blk0 range). r6-proven inner loop:
// 32 KB LDS single-buffer, kb OUTER / tap INNER, 2 barriers per step,
// global_load_lds width-16, XOR chunk swizzle via pre-swizzled global source,
// per-level bijective XCD chunk swizzle.
// ---------------------------------------------------------------------------
__global__ __launch_bounds__(256) void conv3x3_mega(ConvP P0, ConvP P1, ConvP P2,
                                                    const short* zbuf) {
  __shared__ __align__(16) short As[128 * 64];
  __shared__ __align__(16) short Xs[128 * 64];

  int bid = blockIdx.x;
  ConvP P = bid >= P2.blk0 ? P2 : (bid >= P1.blk0 ? P1 : P0);
  const int C = P.C, H = P.H, W = P.W, HW = P.HW, nb_m = P.nb_m, nwg = P.nwg;

  // bijective XCD chunk swizzle within the level (nwg % 8 == 0 always here)
  const int orig = bid - P.blk0;
  const int q = nwg >> 3, rr = nwg & 7;
  const int xcd = orig & 7;
  const int wg = (xcd < rr ? xcd * (q + 1) : rr * (q + 1) + (xcd - rr) * q) + (orig >> 3);
  int m, n;
  if (P.mfast) { m = wg % nb_m; n = wg / nb_m; }
  else         { const int nb_n = nwg / nb_m; n = wg % nb_n; m = wg / nb_n; }
  const int mt0 = m * 128;
  const int nt0 = n * 128;
  const int M2 = nb_m * 128;

  const int tid = threadIdx.x;
  const int lane = tid & 63;
  const int wave = tid >> 6;
  const int wm = (wave >> 1) * 64;
  const int wn = (wave & 1) * 64;
  const int s = tid & 7;

  int xs_x[4], xs_y[4];
  int xs_base[4];
  int as_base[4];
#pragma unroll
  for (int r = 0; r < 4; ++r) {
    int cl = r * 32 + (tid >> 3);
    int nn = nt0 + cl;
    int b = nn / HW; int p = nn - b * HW;
    int y = p / W;  int x = p - y * W;
    xs_x[r] = x; xs_y[r] = y;
    int swz = (s ^ (cl & 7)) * 8;
    xs_base[r] = ((b * H + y) * W + x) * C + swz;
    as_base[r] = (mt0 + cl) * C + swz;
  }

  f32x4 acc[4][4];
#pragma unroll
  for (int a_ = 0; a_ < 4; ++a_)
#pragma unroll
    for (int b_ = 0; b_ < 4; ++b_) acc[a_][b_] = (f32x4){0.f, 0.f, 0.f, 0.f};

  const int nkb = C >> 6;
  const long MC = (long)M2 * C;
  const short* gzb = zbuf + s * 8;

  for (int kb = 0; kb < nkb; ++kb) {
    const int kb64 = kb << 6;
    for (int t = 0; t < 9; ++t) {
      const int dy = t / 3 - 1, dx = t - (t / 3) * 3 - 1;
      const int doff = (dy * W + dx) * C + kb64;
      const short* gap = P.wt + (long)t * MC + kb64;
#pragma unroll
      for (int r = 0; r < 4; ++r) {
        gload_lds16(gap + as_base[r], (char*)As + r * 4096 + tid * 16);
        bool ok = ((unsigned)(xs_y[r] + dy) < (unsigned)H) &
                  ((unsigned)(xs_x[r] + dx) < (unsigned)W);
        const short* gx = ok ? P.fb + xs_base[r] + doff : gzb;
        gload_lds16(gx, (char*)Xs + r * 4096 + tid * 16);
      }
      __syncthreads();

#pragma unroll
      for (int ks = 0; ks < 2; ++ks) {
        bf16x8 af[4], xf[4];
#pragma unroll
        for (int mf = 0; mf < 4; ++mf) {
          int row = wm + mf * 16 + (lane & 15);
          int c = (ks * 4 + (lane >> 4)) ^ (row & 7);
          af[mf] = as_bf16x8(*(const int4*)((const char*)As + row * 128 + c * 16));
        }
#pragma unroll
        for (int nf = 0; nf < 4; ++nf) {
          int col = wn + nf * 16 + (lane & 15);
          int c = (ks * 4 + (lane >> 4)) ^ (col & 7);
          xf[nf] = as_bf16x8(*(const int4*)((const char*)Xs + col * 128 + c * 16));
        }
        __builtin_amdgcn_s_setprio(1);
#pragma unroll
        for (int mf = 0; mf < 4; ++mf)
#pragma unroll
          for (int nf = 0; nf < 4; ++nf)
            acc[mf][nf] = __builtin_amdgcn_mfma_f32_16x16x32_bf16(af[mf], xf[nf],
                                                                  acc[mf][nf], 0, 0, 0);
        __builtin_amdgcn_s_setprio(0);
      }
      __syncthreads();
    }
  }

  // epilogue: + bias (rows < C from bA, rows >= C from bB), bf16 NCHW
  int nb[4], np[4];
#pragma unroll
  for (int nf = 0; nf < 4; ++nf) {
    int nn = nt0 + wn + nf * 16 + (lane & 15);
    nb[nf] = nn / HW;
    np[nf] = nn - nb[nf] * HW;
  }
#pragma unroll
  for (int mf = 0; mf < 4; ++mf) {
    int co0 = mt0 + wm + mf * 16 + (lane >> 4) * 4;
#pragma unroll
    for (int rg = 0; rg < 4; ++rg) {
      int co = co0 + rg;
      float bv = co < C ? P.bA[co] : P.bB[co - C];
#pragma unroll
      for (int nf = 0; nf < 4; ++nf) {
        float v = acc[mf][nf][rg] + bv;
        P.h[((long)nb[nf] * M2 + co) * HW + np[nf]] = f2bf(v);
      }
    }
  }
}

// ---------------------------------------------------------------------------
// Fused decode: LDS-tiled 1x1 conv (C->NOUT) + bias + decode; all levels in
// one launch per NOUT. (r4-proven body.)
// ---------------------------------------------------------------------------
template <int NOUT>
__global__ __launch_bounds__(256) void decode_mega(DeP D0, DeP D1, DeP D2,
                                                   float* __restrict__ out) {
  __shared__ float htile[32][33];
  __shared__ float wtileT[32][32];
  __shared__ float otile[32][NOUT + 1];
  int bid = blockIdx.x;
  DeP D = bid >= D2.blk0 ? D2 : (bid >= D1.blk0 ? D1 : D0);
  int l = bid - D.blk0;
  const int pt = l % D.ptiles;
  const int bl = l / D.ptiles;
  const int C = D.C, Ct = D.Ct, H = D.H, W = D.W, HW = H * W;
  const int t = threadIdx.x;
  const int p0 = pt * 32;
  const int px = t & 31, og = t >> 5;

  float acc[4] = {0.f, 0.f, 0.f, 0.f};
  const int nch = C >> 5;
  for (int ch = 0; ch < nch; ++ch) {
    const int c0 = ch << 5;
    {
      int cl = t >> 3, pl = (t & 7) * 4;
      int pr = p0 + pl;
      if (pr > HW - 4) pr = HW - 4;  // clamp; dup columns belong to dead px
      const short4 v = *(const short4*)(D.h + ((long)bl * Ct + c0 + cl) * HW + pr);
      htile[cl][pl + 0] = bf2f(v.x);
      htile[cl][pl + 1] = bf2f(v.y);
      htile[cl][pl + 2] = bf2f(v.z);
      htile[cl][pl + 3] = bf2f(v.w);
    }
    {
      int j = t >> 3, cl = (t & 7) * 4;
      if (j < NOUT) {
        const float4 v = *(const float4*)(D.wb + (long)j * C + c0 + cl);
        wtileT[cl + 0][j] = v.x;
        wtileT[cl + 1][j] = v.y;
        wtileT[cl + 2][j] = v.z;
        wtileT[cl + 3][j] = v.w;
      } else {
        wtileT[cl + 0][j] = 0.f;
        wtileT[cl + 1][j] = 0.f;
        wtileT[cl + 2][j] = 0.f;
        wtileT[cl + 3][j] = 0.f;
      }
    }
    __syncthreads();
#pragma unroll
    for (int c = 0; c < 32; ++c) {
      float v = htile[c][px];
      const float4 wv = *(const float4*)&wtileT[c][og * 4];
      acc[0] = fmaf(v, wv.x, acc[0]);
      acc[1] = fmaf(v, wv.y, acc[1]);
      acc[2] = fmaf(v, wv.z, acc[2]);
      acc[3] = fmaf(v, wv.w, acc[3]);
    }
    __syncthreads();
  }
#pragma unroll
  for (int g = 0; g < 4; ++g) {
    int j = og * 4 + g;
    if (j < NOUT) otile[px][j] = acc[g] + D.bb[j];
  }
  __syncthreads();

  if (t < 96) {
    const int pxx = t / 3, a = t - (t / 3) * 3;
    const int p = p0 + pxx;
    if (p < HW) {
      float* o = out + ((size_t)(D.b0 + bl) * TOT_ANCH + D.loff + (size_t)a * HW + p) * 17;
      if (NOUT == 24) {
        const int y = p / W, x = p - (p / W) * W;
        float s0 = sig_(otile[pxx][a * 8 + 0]);
        float s1 = sig_(otile[pxx][a * 8 + 1]);
        float sw = sig_(otile[pxx][a * 8 + 2]) * 2.f;
        float sh = sig_(otile[pxx][a * 8 + 3]) * 2.f;
        o[0] = (s0 * 2.f - 0.5f + (float)x) * D.stride;
        o[1] = (s1 * 2.f - 0.5f + (float)y) * D.stride;
        o[2] = sw * sw * d_anch[D.lvl][a][0];
        o[3] = sh * sh * d_anch[D.lvl][a][1];
        o[4] = sig_(otile[pxx][a * 8 + 4]);
        o[5] = sig_(otile[pxx][a * 8 + 5]);
        o[6] = sig_(otile[pxx][a * 8 + 6]);
        o[7] = sig_(otile[pxx][a * 8 + 7]);
      } else {
        float v0 = otile[pxx][a * 9 + 0], v1 = otile[pxx][a * 9 + 1];
        float v2 = otile[pxx][a * 9 + 2], v3 = otile[pxx][a * 9 + 3];
        float v4 = otile[pxx][a * 9 + 4], v5 = otile[pxx][a * 9 + 5];
        float v6 = otile[pxx][a * 9 + 6], v7 = otile[pxx][a * 9 + 7];
        float v8 = otile[pxx][a * 9 + 8];
        float n0 = fmaxf(sqrtf(v2 * v2 + v3 * v3), 1e-12f);
        float n1 = fmaxf(sqrtf(v4 * v4 + v5 * v5), 1e-12f);
        o[8] = v0;
        o[9] = v1;
        o[10] = v2 / n0;
        o[11] = v3 / n0;
        o[12] = v4 / n1;
        o[13] = v5 / n1;
        o[14] = sig_(v6) * 2.f - 1.f;
        o[15] = sig_(v7) * 2.f - 1.f;
        o[16] = sig_(v8) * 2.f - 1.f;
      }
    }
  }
}

// ---------------------------------------------------------------------------

static inline size_t al256(size_t x) { return (x + 255) & ~(size_t)255; }

extern "C" void kernel_launch(void* const* d_in, const int* in_sizes, int n_in,
                              void* d_out, int out_size, void* d_ws, size_t ws_size,
                              hipStream_t stream) {
  (void)in_sizes; (void)n_in; (void)out_size;
  char* ws = (char*)d_ws;
  float* out = (float*)d_out;

  hipMemsetAsync(ws, 0, 256, stream);  // zero page for OOB tap columns
  const short* zb = (const short*)ws;

  struct Lvl { int C, H, W, loff; float stride; };
  const Lvl L[3] = {{256, 80, 80, 0, 8.f}, {512, 40, 40, 19200, 16.f},
                    {1024, 20, 20, 24000, 32.f}};
  const int B = 8;

  const float* f_[3]; const float *w2a_[3], *b2a_[3], *w2b_[3], *b2b_[3];
  const float *w3a_[3], *b3a_[3], *w3b_[3], *b3b_[3];
  int HW_[3], ptiles_[3], c32_[3], nbm_[3], mfast_[3];
  long CC_[3];
  size_t fbB_[3], wtB_[3], hB_[3];
  for (int i = 0; i < 3; ++i) {
    f_[i]   = (const float*)d_in[9 * i + 0];
    w2a_[i] = (const float*)d_in[9 * i + 1];
    b2a_[i] = (const float*)d_in[9 * i + 2];
    w2b_[i] = (const float*)d_in[9 * i + 3];
    b2b_[i] = (const float*)d_in[9 * i + 4];
    w3a_[i] = (const float*)d_in[9 * i + 5];
    b3a_[i] = (const float*)d_in[9 * i + 6];
    w3b_[i] = (const float*)d_in[9 * i + 7];
    b3b_[i] = (const float*)d_in[9 * i + 8];
    const int C = L[i].C;
    HW_[i] = L[i].H * L[i].W;
    ptiles_[i] = (HW_[i] + 31) / 32;
    c32_[i] = C / 32;
    nbm_[i] = (2 * C) / 128;
    CC_[i] = (long)C * C;
    fbB_[i] = (size_t)B * HW_[i] * C * 2;        // bf16 NHWC
    wtB_[i] = (size_t)36 * CC_[i];               // 9 * 2C * C bf16 = 36*CC bytes
    hB_[i]  = (size_t)B * HW_[i] * 2 * C * 2;    // bf16 NCHW, M=2C
    mfast_[i] = ((size_t)B * HW_[i] * C >= (size_t)18 * CC_[i]) ? 1 : 0;
  }

  // ---- mega plan: everything resident at once (~188 MB) ----
  size_t off = 256;
  size_t fb_o[3], wt_o[3], h_o[3];
  for (int i = 0; i < 3; ++i) { fb_o[i] = off; off += al256(fbB_[i]); }
  for (int i = 0; i < 3; ++i) { wt_o[i] = off; off += al256(wtB_[i]); }
  for (int i = 0; i < 3; ++i) { h_o[i] = off; off += al256(hB_[i]); }

  if (off <= ws_size) {
    short* fb[3]; short* wtb[3]; short* hb[3];
    for (int i = 0; i < 3; ++i) {
      fb[i] = (short*)(ws + fb_o[i]);
      wtb[i] = (short*)(ws + wt_o[i]);
      hb[i] = (short*)(ws + h_o[i]);
    }
    TrP T[3]; int tb = 0;
    for (int i = 0; i < 3; ++i) {
      T[i] = TrP{f_[i], fb[i], L[i].C, HW_[i], ptiles_[i], c32_[i], tb};
      tb += ptiles_[i] * c32_[i] * B;
    }
    to_nhwc_mega<<<tb, 256, 0, stream>>>(T[0], T[1], T[2]);

    WtP J[6]; int jb = 0;
    for (int i = 0; i < 3; ++i) {
      J[2 * i]     = WtP{w2a_[i], wtb[i], CC_[i], 2 * CC_[i], 0, jb};
      jb += (int)(CC_[i] / 256);
      J[2 * i + 1] = WtP{w3a_[i], wtb[i], CC_[i], 2 * CC_[i], CC_[i], jb};
      jb += (int)(CC_[i] / 256);
    }
    wt_mega<<<jb, 256, 0, stream>>>(J[0], J[1], J[2], J[3], J[4], J[5]);

    ConvP P[3]; int cb = 0;
    for (int i = 0; i < 3; ++i) {
      int nwg = (B * HW_[i] / 128) * nbm_[i];
      P[i] = ConvP{fb[i], wtb[i], b2a_[i], b3a_[i], hb[i],
                   L[i].C, L[i].H, L[i].W, HW_[i], nbm_[i], nwg, mfast_[i], cb};
      cb += nwg;
    }
    conv3x3_mega<<<cb, 256, 0, stream>>>(P[0], P[1], P[2], zb);

    DeP D2[3], D3[3]; int db = 0;
    for (int i = 0; i < 3; ++i) {
      const int C = L[i].C;
      D2[i] = DeP{hb[i], w2b_[i], b2b_[i], C, 2 * C, L[i].H, L[i].W,
                  0, L[i].loff, ptiles_[i], i, db, L[i].stride};
      D3[i] = DeP{hb[i] + (size_t)C * HW_[i], w3b_[i], b3b_[i], C, 2 * C, L[i].H,
                  L[i].W, 0, L[i].loff, ptiles_[i], i, db, L[i].stride};
      db += ptiles_[i] * B;
    }
    decode_mega<24><<<db, 256, 0, stream>>>(D2[0], D2[1], D2[2], out);
    decode_mega<27><<<db, 256, 0, stream>>>(D3[0], D3[1], D3[2], out);
    return;
  }

  // ---- fallback: per-level passes (r6-equivalent footprint, proven) ----
  for (int i = 0; i < 3; ++i) {
    const int C = L[i].C, HW = HW_[i];
    int Bg = B;
    for (int cand = 1; cand <= 8; cand <<= 1) {
      int bg = B / cand;
      if (((long)bg * HW) % 128) continue;
      size_t need = 256 + al256((size_t)bg * HW * C * 2) + al256(wtB_[i]) +
                    (size_t)bg * HW * 2 * C * 2;
      if (need <= ws_size) { Bg = bg; break; }
    }
    size_t fo = 256;
    size_t wo = fo + al256((size_t)Bg * HW * C * 2);
    size_t ho = wo + al256(wtB_[i]);
    short* fb = (short*)(ws + fo);
    short* wtb = (short*)(ws + wo);
    short* hb = (short*)(ws + ho);

    WtP J0 = WtP{w2a_[i], wtb, CC_[i], 2 * CC_[i], 0, 0};
    WtP J1 = WtP{w3a_[i], wtb, CC_[i], 2 * CC_[i], CC_[i], (int)(CC_[i] / 256)};
    WtP JX = J1; JX.blk0 = INT_MAX;
    wt_mega<<<(int)(2 * CC_[i] / 256), 256, 0, stream>>>(J0, J1, JX, JX, JX, JX);

    const int nbg = B / Bg;
    for (int g = 0; g < nbg; ++g) {
      const int b0 = g * Bg;
      TrP T0 = TrP{f_[i] + (size_t)b0 * C * HW, fb, C, HW, ptiles_[i], c32_[i], 0};
      TrP TX = T0; TX.blk0 = INT_MAX;
      to_nhwc_mega<<<ptiles_[i] * c32_[i] * Bg, 256, 0, stream>>>(T0, TX, TX);

      int nwg = (Bg * HW / 128) * nbm_[i];
      ConvP P0 = ConvP{fb, wtb, b2a_[i], b3a_[i], hb, C, L[i].H, L[i].W, HW,
                       nbm_[i], nwg, mfast_[i], 0};
      ConvP PX = P0; PX.blk0 = INT_MAX;
      conv3x3_mega<<<nwg, 256, 0, stream>>>(P0, PX, PX, zb);

      DeP D0 = DeP{hb, w2b_[i], b2b_[i], C, 2 * C, L[i].H, L[i].W,
                   b0, L[i].loff, ptiles_[i], i, 0, L[i].stride};
      DeP DX = D0; DX.blk0 = INT_MAX;
      decode_mega<24><<<ptiles_[i] * Bg, 256, 0, stream>>>(D0, DX, DX, out);
      DeP D1 = DeP{hb + (size_t)C * HW, w3b_[i], b3b_[i], C, 2 * C, L[i].H, L[i].W,
                   b0, L[i].loff, ptiles_[i], i, 0, L[i].stride};
      DeP DY = D1; DY.blk0 = INT_MAX;
      decode_mega<27><<<ptiles_[i] * Bg, 256, 0, stream>>>(D1, DY, DY, out);
    }
  }
}

// Round 9
// 486.939 us; speedup vs baseline: 36.8479x; 1.1415x over previous
//
#include <hip/hip_runtime.h>
#include <hip/hip_bf16.h>
#include <cstddef>
#include <cstdint>
#include <climits>

#define TOT_ANCH 25200

typedef __bf16 bf16x8 __attribute__((ext_vector_type(8)));
typedef float f32x4 __attribute__((ext_vector_type(4)));

__device__ __forceinline__ float sig_(float x) { return 1.0f / (1.0f + __expf(-x)); }

__device__ __forceinline__ short f2bf(float v) {
  return (short)__builtin_bit_cast(unsigned short, __float2bfloat16(v));
}
__device__ __forceinline__ float bf2f(short v) {
  unsigned int u = ((unsigned int)(unsigned short)v) << 16;
  return __builtin_bit_cast(float, u);
}
__device__ __forceinline__ bf16x8 as_bf16x8(int4 v) { return __builtin_bit_cast(bf16x8, v); }

__device__ __forceinline__ void gload_lds16(const void* g, void* l) {
  __builtin_amdgcn_global_load_lds((const __attribute__((address_space(1))) void*)g,
                                   (__attribute__((address_space(3))) void*)l, 16, 0, 0);
}

// anchors[level][a][2]
__device__ const float d_anch[3][3][2] = {
    {{10.f, 13.f}, {16.f, 30.f}, {33.f, 23.f}},
    {{30.f, 61.f}, {62.f, 45.f}, {59.f, 119.f}},
    {{116.f, 90.f}, {156.f, 198.f}, {373.f, 326.f}}};

// --------------------------- param structs (by value) -----------------------
struct TrP {  // f32 NCHW -> bf16 NHWC
  const float* f; short* fb; int C, HW, ptiles, c32, blk0;
};
struct WtP {  // OIHW 3x3 f32 -> [t][o][i] bf16 (off0 selects branch row block)
  const float* w; short* dst; long CC, MC, off0; int blk0;
};
struct ConvP {
  const short* fb; const short* wt; const float* bA; const float* bB; short* h;
  int C, H, W, HW, nb_m, nwg, mfast, blk0;
};
struct DeP {
  const short* h; const float* wb; const float* bb;
  int C, Ct, H, W, b0, loff, ptiles, lvl, blk0, nout; float stride;
};

// ---------------------------------------------------------------------------
// aux: transpose (blocks < wt_blk0) + weight transform (blocks >= wt_blk0),
// all levels/branches in ONE launch. Branch is block-uniform.
// ---------------------------------------------------------------------------
__global__ __launch_bounds__(256) void aux_mega(TrP T0, TrP T1, TrP T2,
                                                WtP J0, WtP J1, WtP J2,
                                                WtP J3, WtP J4, WtP J5, int wt_blk0) {
  __shared__ short tile[32][33];
  int bid = blockIdx.x;
  if (bid >= wt_blk0) {
    WtP J = bid >= J5.blk0 ? J5 : bid >= J4.blk0 ? J4 : bid >= J3.blk0 ? J3 :
            bid >= J2.blk0 ? J2 : bid >= J1.blk0 ? J1 : J0;
    long oi = (long)(bid - J.blk0) * 256 + threadIdx.x;
    if (oi >= J.CC) return;
#pragma unroll
    for (int t = 0; t < 9; ++t) J.dst[t * J.MC + J.off0 + oi] = f2bf(J.w[oi * 9 + t]);
    return;
  }
  TrP T = bid >= T2.blk0 ? T2 : (bid >= T1.blk0 ? T1 : T0);
  int l = bid - T.blk0;
  const int pt = l % T.ptiles; l /= T.ptiles;
  const int cg = l % T.c32;
  const int b = l / T.c32;
  const int p0 = pt * 32, c0 = cg * 32, HW = T.HW, C = T.C;
  const int t = threadIdx.x;
  {
    int cl = t >> 3, pl = (t & 7) * 4;
    int pr = p0 + pl;
    if (pr > HW - 4) pr = HW - 4;  // clamp: stays %4==0, dup handled below
    const float4 v = *(const float4*)(T.f + ((long)b * C + c0 + cl) * HW + pr);
    tile[cl][pl + 0] = f2bf(v.x);
    tile[cl][pl + 1] = f2bf(v.y);
    tile[cl][pl + 2] = f2bf(v.z);
    tile[cl][pl + 3] = f2bf(v.w);
  }
  __syncthreads();
  {
    int pl = t >> 3, cl = (t & 7) * 4;
    int pp = p0 + pl;
    if (pp < HW) {
      int k = pl >> 2;
      int start = p0 + 4 * k;
      if (start > HW - 4) start = HW - 4;
      int col = (start - p0) + (pp - start);
      short4 o;
      o.x = tile[cl + 0][col];
      o.y = tile[cl + 1][col];
      o.z = tile[cl + 2][col];
      o.w = tile[cl + 3][col];
      *(short4*)(T.fb + ((long)b * HW + pp) * C + c0 + cl) = o;
    }
  }
}

// ---------------------------------------------------------------------------
// Implicit-GEMM conv3x3 (pad 1), branches fused on M (M2 = nb_m*128), ALL
// LEVELS in one launch, LONGEST-FIRST (host passes L2,L1,L0). r6-proven inner
// loop: 32 KB LDS single-buffer, kb OUTER / tap INNER, 2 barriers/step,
// global_load_lds width-16, XOR chunk swizzle via pre-swizzled global source,
// per-level bijective XCD chunk swizzle. launch_bounds(256,3): 144 unified
// regs < 170 cap -> no spill, hints 3 blocks/CU.
// ---------------------------------------------------------------------------
__global__ __launch_bounds__(256, 3) void conv3x3_mega(ConvP P0, ConvP P1, ConvP P2,
                                                       const short* zbuf) {
  __shared__ __align__(16) short As[128 * 64];
  __shared__ __align__(16) short Xs[128 * 64];

  int bid = blockIdx.x;
  ConvP P = bid >= P2.blk0 ? P2 : (bid >= P1.blk0 ? P1 : P0);
  const int C = P.C, H = P.H, W = P.W, HW = P.HW, nb_m = P.nb_m, nwg = P.nwg;

  // bijective XCD chunk swizzle within the level (nwg % 8 == 0 always here)
  const int orig = bid - P.blk0;
  const int q = nwg >> 3, rr = nwg & 7;
  const int xcd = orig & 7;
  const int wg = (xcd < rr ? xcd * (q + 1) : rr * (q + 1) + (xcd - rr) * q) + (orig >> 3);
  int m, n;
  if (P.mfast) { m = wg % nb_m; n = wg / nb_m; }
  else         { const int nb_n = nwg / nb_m; n = wg % nb_n; m = wg / nb_n; }
  const int mt0 = m * 128;
  const int nt0 = n * 128;
  const int M2 = nb_m * 128;

  const int tid = threadIdx.x;
  const int lane = tid & 63;
  const int wave = tid >> 6;
  const int wm = (wave >> 1) * 64;
  const int wn = (wave & 1) * 64;
  const int s = tid & 7;

  int xs_x[4], xs_y[4];
  int xs_base[4];
  int as_base[4];
#pragma unroll
  for (int r = 0; r < 4; ++r) {
    int cl = r * 32 + (tid >> 3);
    int nn = nt0 + cl;
    int b = nn / HW; int p = nn - b * HW;
    int y = p / W;  int x = p - y * W;
    xs_x[r] = x; xs_y[r] = y;
    int swz = (s ^ (cl & 7)) * 8;
    xs_base[r] = ((b * H + y) * W + x) * C + swz;
    as_base[r] = (mt0 + cl) * C + swz;
  }

  f32x4 acc[4][4];
#pragma unroll
  for (int a_ = 0; a_ < 4; ++a_)
#pragma unroll
    for (int b_ = 0; b_ < 4; ++b_) acc[a_][b_] = (f32x4){0.f, 0.f, 0.f, 0.f};

  const int nkb = C >> 6;
  const long MC = (long)M2 * C;
  const short* gzb = zbuf + s * 8;

  for (int kb = 0; kb < nkb; ++kb) {
    const int kb64 = kb << 6;
    for (int t = 0; t < 9; ++t) {
      const int dy = t / 3 - 1, dx = t - (t / 3) * 3 - 1;
      const int doff = (dy * W + dx) * C + kb64;
      const short* gap = P.wt + (long)t * MC + kb64;
#pragma unroll
      for (int r = 0; r < 4; ++r) {
        gload_lds16(gap + as_base[r], (char*)As + r * 4096 + tid * 16);
        bool ok = ((unsigned)(xs_y[r] + dy) < (unsigned)H) &
                  ((unsigned)(xs_x[r] + dx) < (unsigned)W);
        const short* gx = ok ? P.fb + xs_base[r] + doff : gzb;
        gload_lds16(gx, (char*)Xs + r * 4096 + tid * 16);
      }
      __syncthreads();

#pragma unroll
      for (int ks = 0; ks < 2; ++ks) {
        bf16x8 af[4], xf[4];
#pragma unroll
        for (int mf = 0; mf < 4; ++mf) {
          int row = wm + mf * 16 + (lane & 15);
          int c = (ks * 4 + (lane >> 4)) ^ (row & 7);
          af[mf] = as_bf16x8(*(const int4*)((const char*)As + row * 128 + c * 16));
        }
#pragma unroll
        for (int nf = 0; nf < 4; ++nf) {
          int col = wn + nf * 16 + (lane & 15);
          int c = (ks * 4 + (lane >> 4)) ^ (col & 7);
          xf[nf] = as_bf16x8(*(const int4*)((const char*)Xs + col * 128 + c * 16));
        }
        __builtin_amdgcn_s_setprio(1);
#pragma unroll
        for (int mf = 0; mf < 4; ++mf)
#pragma unroll
          for (int nf = 0; nf < 4; ++nf)
            acc[mf][nf] = __builtin_amdgcn_mfma_f32_16x16x32_bf16(af[mf], xf[nf],
                                                                  acc[mf][nf], 0, 0, 0);
        __builtin_amdgcn_s_setprio(0);
      }
      __syncthreads();
    }
  }

  // epilogue: + bias (rows < C from bA, rows >= C from bB), bf16 NCHW
  int nb[4], np[4];
#pragma unroll
  for (int nf = 0; nf < 4; ++nf) {
    int nn = nt0 + wn + nf * 16 + (lane & 15);
    nb[nf] = nn / HW;
    np[nf] = nn - nb[nf] * HW;
  }
#pragma unroll
  for (int mf = 0; mf < 4; ++mf) {
    int co0 = mt0 + wm + mf * 16 + (lane >> 4) * 4;
#pragma unroll
    for (int rg = 0; rg < 4; ++rg) {
      int co = co0 + rg;
      float bv = co < C ? P.bA[co] : P.bB[co - C];
#pragma unroll
      for (int nf = 0; nf < 4; ++nf) {
        float v = acc[mf][nf][rg] + bv;
        P.h[((long)nb[nf] * M2 + co) * HW + np[nf]] = f2bf(v);
      }
    }
  }
}

// ---------------------------------------------------------------------------
// decode: LDS-tiled 1x1 conv (C->nout) + bias + decode; BOTH branches x all
// levels in ONE launch (6 jobs, runtime nout 24/27), longest-first.
// ---------------------------------------------------------------------------
__global__ __launch_bounds__(256) void decode_mega2(DeP D0, DeP D1, DeP D2,
                                                    DeP D3, DeP D4, DeP D5,
                                                    float* __restrict__ out) {
  __shared__ float htile[32][33];
  __shared__ float wtileT[32][32];
  __shared__ float otile[32][28];
  int bid = blockIdx.x;
  DeP D = bid >= D5.blk0 ? D5 : bid >= D4.blk0 ? D4 : bid >= D3.blk0 ? D3 :
          bid >= D2.blk0 ? D2 : bid >= D1.blk0 ? D1 : D0;
  int l = bid - D.blk0;
  const int pt = l % D.ptiles;
  const int bl = l / D.ptiles;
  const int C = D.C, Ct = D.Ct, H = D.H, W = D.W, HW = H * W;
  const int nout = D.nout;
  const int t = threadIdx.x;
  const int p0 = pt * 32;
  const int px = t & 31, og = t >> 5;

  float acc[4] = {0.f, 0.f, 0.f, 0.f};
  const int nch = C >> 5;
  for (int ch = 0; ch < nch; ++ch) {
    const int c0 = ch << 5;
    {
      int cl = t >> 3, pl = (t & 7) * 4;
      int pr = p0 + pl;
      if (pr > HW - 4) pr = HW - 4;  // clamp; dup columns belong to dead px
      const short4 v = *(const short4*)(D.h + ((long)bl * Ct + c0 + cl) * HW + pr);
      htile[cl][pl + 0] = bf2f(v.x);
      htile[cl][pl + 1] = bf2f(v.y);
      htile[cl][pl + 2] = bf2f(v.z);
      htile[cl][pl + 3] = bf2f(v.w);
    }
    {
      int j = t >> 3, cl = (t & 7) * 4;
      if (j < nout) {
        const float4 v = *(const float4*)(D.wb + (long)j * C + c0 + cl);
        wtileT[cl + 0][j] = v.x;
        wtileT[cl + 1][j] = v.y;
        wtileT[cl + 2][j] = v.z;
        wtileT[cl + 3][j] = v.w;
      } else {
        wtileT[cl + 0][j] = 0.f;
        wtileT[cl + 1][j] = 0.f;
        wtileT[cl + 2][j] = 0.f;
        wtileT[cl + 3][j] = 0.f;
      }
    }
    __syncthreads();
#pragma unroll
    for (int c = 0; c < 32; ++c) {
      float v = htile[c][px];
      const float4 wv = *(const float4*)&wtileT[c][og * 4];
      acc[0] = fmaf(v, wv.x, acc[0]);
      acc[1] = fmaf(v, wv.y, acc[1]);
      acc[2] = fmaf(v, wv.z, acc[2]);
      acc[3] = fmaf(v, wv.w, acc[3]);
    }
    __syncthreads();
  }
#pragma unroll
  for (int g = 0; g < 4; ++g) {
    int j = og * 4 + g;
    if (j < nout) otile[px][j] = acc[g] + D.bb[j];
  }
  __syncthreads();

  if (t < 96) {
    const int pxx = t / 3, a = t - (t / 3) * 3;
    const int p = p0 + pxx;
    if (p < HW) {
      float* o = out + ((size_t)(D.b0 + bl) * TOT_ANCH + D.loff + (size_t)a * HW + p) * 17;
      if (nout == 24) {
        const int y = p / W, x = p - (p / W) * W;
        float s0 = sig_(otile[pxx][a * 8 + 0]);
        float s1 = sig_(otile[pxx][a * 8 + 1]);
        float sw = sig_(otile[pxx][a * 8 + 2]) * 2.f;
        float sh = sig_(otile[pxx][a * 8 + 3]) * 2.f;
        o[0] = (s0 * 2.f - 0.5f + (float)x) * D.stride;
        o[1] = (s1 * 2.f - 0.5f + (float)y) * D.stride;
        o[2] = sw * sw * d_anch[D.lvl][a][0];
        o[3] = sh * sh * d_anch[D.lvl][a][1];
        o[4] = sig_(otile[pxx][a * 8 + 4]);
        o[5] = sig_(otile[pxx][a * 8 + 5]);
        o[6] = sig_(otile[pxx][a * 8 + 6]);
        o[7] = sig_(otile[pxx][a * 8 + 7]);
      } else {
        float v0 = otile[pxx][a * 9 + 0], v1 = otile[pxx][a * 9 + 1];
        float v2 = otile[pxx][a * 9 + 2], v3 = otile[pxx][a * 9 + 3];
        float v4 = otile[pxx][a * 9 + 4], v5 = otile[pxx][a * 9 + 5];
        float v6 = otile[pxx][a * 9 + 6], v7 = otile[pxx][a * 9 + 7];
        float v8 = otile[pxx][a * 9 + 8];
        float n0 = fmaxf(sqrtf(v2 * v2 + v3 * v3), 1e-12f);
        float n1 = fmaxf(sqrtf(v4 * v4 + v5 * v5), 1e-12f);
        o[8] = v0;
        o[9] = v1;
        o[10] = v2 / n0;
        o[11] = v3 / n0;
        o[12] = v4 / n1;
        o[13] = v5 / n1;
        o[14] = sig_(v6) * 2.f - 1.f;
        o[15] = sig_(v7) * 2.f - 1.f;
        o[16] = sig_(v8) * 2.f - 1.f;
      }
    }
  }
}

// ---------------------------------------------------------------------------

static inline size_t al256(size_t x) { return (x + 255) & ~(size_t)255; }

extern "C" void kernel_launch(void* const* d_in, const int* in_sizes, int n_in,
                              void* d_out, int out_size, void* d_ws, size_t ws_size,
                              hipStream_t stream) {
  (void)in_sizes; (void)n_in; (void)out_size;
  char* ws = (char*)d_ws;
  float* out = (float*)d_out;

  hipMemsetAsync(ws, 0, 256, stream);  // zero page for OOB tap columns
  const short* zb = (const short*)ws;

  struct Lvl { int C, H, W, loff; float stride; };
  const Lvl L[3] = {{256, 80, 80, 0, 8.f}, {512, 40, 40, 19200, 16.f},
                    {1024, 20, 20, 24000, 32.f}};
  const int B = 8;
  const int ord[3] = {2, 1, 0};  // longest blocks first

  const float* f_[3]; const float *w2a_[3], *b2a_[3], *w2b_[3], *b2b_[3];
  const float *w3a_[3], *b3a_[3], *w3b_[3], *b3b_[3];
  int HW_[3], ptiles_[3], c32_[3], nbm_[3], mfast_[3];
  long CC_[3];
  size_t fbB_[3], wtB_[3], hB_[3];
  for (int i = 0; i < 3; ++i) {
    f_[i]   = (const float*)d_in[9 * i + 0];
    w2a_[i] = (const float*)d_in[9 * i + 1];
    b2a_[i] = (const float*)d_in[9 * i + 2];
    w2b_[i] = (const float*)d_in[9 * i + 3];
    b2b_[i] = (const float*)d_in[9 * i + 4];
    w3a_[i] = (const float*)d_in[9 * i + 5];
    b3a_[i] = (const float*)d_in[9 * i + 6];
    w3b_[i] = (const float*)d_in[9 * i + 7];
    b3b_[i] = (const float*)d_in[9 * i + 8];
    const int C = L[i].C;
    HW_[i] = L[i].H * L[i].W;
    ptiles_[i] = (HW_[i] + 31) / 32;
    c32_[i] = C / 32;
    nbm_[i] = (2 * C) / 128;
    CC_[i] = (long)C * C;
    fbB_[i] = (size_t)B * HW_[i] * C * 2;        // bf16 NHWC
    wtB_[i] = (size_t)36 * CC_[i];               // 9 * 2C * C bf16 = 36*CC bytes
    hB_[i]  = (size_t)B * HW_[i] * 2 * C * 2;    // bf16 NCHW, M=2C
    mfast_[i] = ((size_t)B * HW_[i] * C >= (size_t)18 * CC_[i]) ? 1 : 0;
  }

  // ---- mega plan: everything resident at once (~188 MB) ----
  size_t off = 256;
  size_t fb_o[3], wt_o[3], h_o[3];
  for (int i = 0; i < 3; ++i) { fb_o[i] = off; off += al256(fbB_[i]); }
  for (int i = 0; i < 3; ++i) { wt_o[i] = off; off += al256(wtB_[i]); }
  for (int i = 0; i < 3; ++i) { h_o[i] = off; off += al256(hB_[i]); }

  if (off <= ws_size) {
    short* fb[3]; short* wtb[3]; short* hb[3];
    for (int i = 0; i < 3; ++i) {
      fb[i] = (short*)(ws + fb_o[i]);
      wtb[i] = (short*)(ws + wt_o[i]);
      hb[i] = (short*)(ws + h_o[i]);
    }
    // 1 aux launch: transpose (all levels) + weight transform (6 jobs)
    TrP T[3]; int tb = 0;
    for (int i = 0; i < 3; ++i) {
      T[i] = TrP{f_[i], fb[i], L[i].C, HW_[i], ptiles_[i], c32_[i], tb};
      tb += ptiles_[i] * c32_[i] * B;
    }
    WtP J[6]; int jb = tb;
    for (int i = 0; i < 3; ++i) {
      J[2 * i]     = WtP{w2a_[i], wtb[i], CC_[i], 2 * CC_[i], 0, jb};
      jb += (int)(CC_[i] / 256);
      J[2 * i + 1] = WtP{w3a_[i], wtb[i], CC_[i], 2 * CC_[i], CC_[i], jb};
      jb += (int)(CC_[i] / 256);
    }
    aux_mega<<<jb, 256, 0, stream>>>(T[0], T[1], T[2], J[0], J[1], J[2], J[3], J[4],
                                     J[5], tb);

    // 1 conv launch, all levels, LONGEST-FIRST (L2, L1, L0)
    ConvP P[3]; int cb = 0;
    for (int k = 0; k < 3; ++k) {
      const int i = ord[k];
      int nwg = (B * HW_[i] / 128) * nbm_[i];
      P[k] = ConvP{fb[i], wtb[i], b2a_[i], b3a_[i], hb[i],
                   L[i].C, L[i].H, L[i].W, HW_[i], nbm_[i], nwg, mfast_[i], cb};
      cb += nwg;
    }
    conv3x3_mega<<<cb, 256, 0, stream>>>(P[0], P[1], P[2], zb);

    // 1 decode launch: both branches x all levels, longest-first
    DeP D[6]; int db = 0;
    for (int k = 0; k < 3; ++k) {
      const int i = ord[k];
      const int C = L[i].C;
      D[2 * k] = DeP{hb[i], w2b_[i], b2b_[i], C, 2 * C, L[i].H, L[i].W,
                     0, L[i].loff, ptiles_[i], i, db, 24, L[i].stride};
      db += ptiles_[i] * B;
      D[2 * k + 1] = DeP{hb[i] + (size_t)C * HW_[i], w3b_[i], b3b_[i], C, 2 * C,
                         L[i].H, L[i].W, 0, L[i].loff, ptiles_[i], i, db, 27,
                         L[i].stride};
      db += ptiles_[i] * B;
    }
    decode_mega2<<<db, 256, 0, stream>>>(D[0], D[1], D[2], D[3], D[4], D[5], out);
    return;
  }

  // ---- fallback: per-level passes (r6-equivalent footprint, proven) ----
  for (int i = 0; i < 3; ++i) {
    const int C = L[i].C, HW = HW_[i];
    int Bg = B;
    for (int cand = 1; cand <= 8; cand <<= 1) {
      int bg = B / cand;
      if (((long)bg * HW) % 128) continue;
      size_t need = 256 + al256((size_t)bg * HW * C * 2) + al256(wtB_[i]) +
                    (size_t)bg * HW * 2 * C * 2;
      if (need <= ws_size) { Bg = bg; break; }
    }
    size_t fo = 256;
    size_t wo = fo + al256((size_t)Bg * HW * C * 2);
    size_t ho = wo + al256(wtB_[i]);
    short* fb = (short*)(ws + fo);
    short* wtb = (short*)(ws + wo);
    short* hb = (short*)(ws + ho);

    // weight transform once per level (wt-only aux launch)
    TrP TZ{};
    WtP J0 = WtP{w2a_[i], wtb, CC_[i], 2 * CC_[i], 0, 0};
    WtP J1 = WtP{w3a_[i], wtb, CC_[i], 2 * CC_[i], CC_[i], (int)(CC_[i] / 256)};
    WtP JX = J1; JX.blk0 = INT_MAX;
    aux_mega<<<(int)(2 * CC_[i] / 256), 256, 0, stream>>>(TZ, TZ, TZ, J0, J1, JX, JX,
                                                          JX, JX, 0);

    const int nbg = B / Bg;
    for (int g = 0; g < nbg; ++g) {
      const int b0 = g * Bg;
      // transpose-only aux launch
      TrP T0 = TrP{f_[i] + (size_t)b0 * C * HW, fb, C, HW, ptiles_[i], c32_[i], 0};
      TrP TX = T0; TX.blk0 = INT_MAX;
      WtP JZ{}; JZ.blk0 = INT_MAX;
      aux_mega<<<ptiles_[i] * c32_[i] * Bg, 256, 0, stream>>>(T0, TX, TX, JZ, JZ, JZ,
                                                              JZ, JZ, JZ, INT_MAX);

      int nwg = (Bg * HW / 128) * nbm_[i];
      ConvP P0 = ConvP{fb, wtb, b2a_[i], b3a_[i], hb, C, L[i].H, L[i].W, HW,
                       nbm_[i], nwg, mfast_[i], 0};
      ConvP PX = P0; PX.blk0 = INT_MAX;
      conv3x3_mega<<<nwg, 256, 0, stream>>>(P0, PX, PX, zb);

      DeP D0 = DeP{hb, w2b_[i], b2b_[i], C, 2 * C, L[i].H, L[i].W,
                   b0, L[i].loff, ptiles_[i], i, 0, 24, L[i].stride};
      DeP D1 = DeP{hb + (size_t)C * HW, w3b_[i], b3b_[i], C, 2 * C, L[i].H, L[i].W,
                   b0, L[i].loff, ptiles_[i], i, ptiles_[i] * Bg, 27, L[i].stride};
      DeP DX = D1; DX.blk0 = INT_MAX;
      decode_mega2<<<2 * ptiles_[i] * Bg, 256, 0, stream>>>(D0, D1, DX, DX, DX, DX,
                                                            out);
    }
  }
}